// Round 12
// baseline (598.119 us; speedup 1.0000x reference)
//
#include <hip/hip_runtime.h>
#include <hip/hip_bf16.h>

#define N_NODES 20000
#define N_REL 32
#define HID 128
#define EMB 16
#define N_EDGES 600000
#define NB (N_NODES * N_REL)   // 640000 bins

typedef __attribute__((ext_vector_type(8))) short  bf8v;   // 8 bf16 (MFMA A/B frag)
typedef __attribute__((ext_vector_type(8))) unsigned short us8v; // 16-byte unit
typedef __attribute__((ext_vector_type(4))) unsigned short us4v; // 8-byte unit
typedef __attribute__((ext_vector_type(4))) float  f4v;    // MFMA C/D frag

__device__ __forceinline__ unsigned short f2b(float f) {
    __hip_bfloat16 h = __float2bfloat16(f);
    return __builtin_bit_cast(unsigned short, h);
}
__device__ __forceinline__ float b2f(unsigned short u) {
    unsigned int x = ((unsigned int)u) << 16;
    return __builtin_bit_cast(float, x);
}

// ======== pre-pass: histogram + all bf16 conversions/transposes ========
#define R_W2 (N_REL * HID * HID)        // 1048576
#define R_XB (N_NODES * 32)             // 640000
#define R_W1 (N_REL * HID * 32)         // 131072
#define R_R1 (HID * 32)                 // 4096
#define R_R2 (HID * HID)                // 16384
#define R_HIST N_EDGES                  // 600000
#define PRE_TOT (R_W2 + R_XB + R_W1 + R_R1 + R_R2 + R_HIST)

__global__ __launch_bounds__(256) void pre1_k(
    const int* __restrict__ dst, const int* __restrict__ et,
    const float* __restrict__ x, const float* __restrict__ W1,
    const float* __restrict__ root1, const float* __restrict__ W2,
    const float* __restrict__ root2,
    int* __restrict__ hist,
    unsigned short* __restrict__ xb, unsigned short* __restrict__ w1t,
    unsigned short* __restrict__ r1t, unsigned short* __restrict__ w2t,
    unsigned short* __restrict__ r2t) {
    int i = blockIdx.x * 256 + threadIdx.x;
    if (i < R_W2) {
        int r = i >> 14, k = (i >> 7) & 127, n = i & 127;
        w2t[(r << 14) + (n << 7) + k] = f2b(W2[i]);
        return;
    }
    i -= R_W2;
    if (i < R_XB) {
        int n = i >> 5, k = i & 31;
        xb[i] = (k < EMB) ? f2b(x[n * EMB + k]) : (unsigned short)0;
        return;
    }
    i -= R_XB;
    if (i < R_W1) {
        int r = i >> 12, n = (i >> 5) & 127, k = i & 31;
        w1t[i] = (k < EMB) ? f2b(W1[(r << 11) + (k << 7) + n]) : (unsigned short)0;
        return;
    }
    i -= R_W1;
    if (i < R_R1) {
        int n = i >> 5, k = i & 31;
        r1t[i] = (k < EMB) ? f2b(root1[(k << 7) + n]) : (unsigned short)0;
        return;
    }
    i -= R_R1;
    if (i < R_R2) {
        int n = i >> 7, k = i & 127;
        r2t[i] = f2b(root2[(k << 7) + n]);
        return;
    }
    i -= R_R2;
    if (i < R_HIST) atomicAdd(&hist[dst[i] * N_REL + et[i]], 1);
}

// ======== 2-level exclusive scan over NB = 625 x 1024 (+ inv fused) ========
__global__ void scan1_k(const int* __restrict__ hist, int* __restrict__ binoff,
                        int* __restrict__ bsum, float* __restrict__ inv) {
    __shared__ int sh[256];
    const int t = threadIdx.x;
    const int base = blockIdx.x * 1024 + t * 4;
    int4 h4 = *(const int4*)(hist + base);
    float4 iv4;
    iv4.x = h4.x > 0 ? 1.0f / h4.x : 0.0f;
    iv4.y = h4.y > 0 ? 1.0f / h4.y : 0.0f;
    iv4.z = h4.z > 0 ? 1.0f / h4.z : 0.0f;
    iv4.w = h4.w > 0 ? 1.0f / h4.w : 0.0f;
    *(float4*)(inv + base) = iv4;
    int ts = h4.x + h4.y + h4.z + h4.w;
    sh[t] = ts;
    __syncthreads();
    for (int o = 1; o < 256; o <<= 1) {
        int v = (t >= o) ? sh[t - o] : 0;
        __syncthreads();
        sh[t] += v;
        __syncthreads();
    }
    int exc = sh[t] - ts;
    binoff[base + 0] = exc;
    binoff[base + 1] = exc + h4.x;
    binoff[base + 2] = exc + h4.x + h4.y;
    binoff[base + 3] = exc + h4.x + h4.y + h4.z;
    if (t == 255) bsum[blockIdx.x] = sh[255];
}

__global__ void scan2_k(const int* __restrict__ bsum, int* __restrict__ bbase) {
    __shared__ int sh[1024];
    const int t = threadIdx.x;
    int v = (t < 625) ? bsum[t] : 0;
    sh[t] = v;
    __syncthreads();
    for (int o = 1; o < 1024; o <<= 1) {
        int u = (t >= o) ? sh[t - o] : 0;
        __syncthreads();
        sh[t] += u;
        __syncthreads();
    }
    if (t < 625) bbase[t] = sh[t] - v;
}

__global__ void scan3_k(int* __restrict__ binoff, const int* __restrict__ bbase,
                        int* __restrict__ cursors) {
    int i = blockIdx.x * 256 + threadIdx.x;
    if (i < NB) {
        int v = binoff[i] + bbase[i >> 10];
        binoff[i] = v;
        cursors[i] = v;
    }
    if (i == 0) binoff[NB] = N_EDGES;
}

__global__ void scatter_k(const int* __restrict__ src, const int* __restrict__ dst,
                          const int* __restrict__ et, int* __restrict__ cursors,
                          int* __restrict__ ssrc) {
    int e = blockIdx.x * 256 + threadIdx.x;
    if (e < 2) ssrc[N_EDGES + e] = 0;   // pad: safe src for empty-bin speculative loads
    if (e < N_EDGES) {
        int b = dst[e] * N_REL + et[e];
        int p = atomicAdd(&cursors[b], 1);
        ssrc[p] = src[e];
    }
}

// ======== wave-autonomous fused gather-GEMM (NO LDS, NO barriers) ========
// 1 wave per block (64 threads). Wave = 16 dst rows x 32 cols.
// grid (5000, N_REL/RG): bx -> d0 = (bx>>3)*32, rtb = 16*(bx&1), cb = 32*((bx>>1)&3);
// y = relation group [y*RG, y*RG+RG), last group adds root transform.
// Lane (m16,q): A-row = d0+rtb+m16, holds k-slice [ks*32+q*8, +8) per K-tile —
// exactly the MFMA A-fragment layout, so the mean-aggregation happens directly
// into fragment registers. Register pipeline: meta 3 iters ahead, srcs 2 ahead,
// G-rows (first 2 edges) 1 ahead. s_waitcnt stalls only this wave; latency is
// hidden by wave-level TLP (1-wave blocks retire & refill independently).
template<int KT, int RG>
__global__ __launch_bounds__(64) void gemm_w(
    const int* __restrict__ binoff, const float* __restrict__ inv,
    const int* __restrict__ ssrc,
    const unsigned short* __restrict__ G,    // bf16 rows [*, KT*32]
    const unsigned short* __restrict__ Bw,   // bf16 W^T [r][128][KT*32]
    const unsigned short* __restrict__ Br,   // bf16 root^T [128][KT*32]
    float* __restrict__ part) {

    constexpr int ROW = KT * 32;

    const int lane = threadIdx.x;
    const int q = lane >> 4, m16 = lane & 15;
    const int q8 = q * 8;
    const int bx = blockIdx.x;
    const int d0  = (bx >> 3) * 32;
    const int rtb = 16 * (bx & 1);
    const int cb  = 32 * ((bx >> 1) & 3);
    const int r0 = blockIdx.y * RG;
    const bool isLast = (blockIdx.y == gridDim.y - 1);
    const int grow = d0 + rtb + m16;         // this lane's A-row (node id)
    const int bbase = grow * N_REL + r0;

    // pipeline state
    int mSo[4], mEo[4]; float mIv[4];
    int sA[2], sB[2];
    us8v g0[KT], g1[KT];

#define LDMETA(s) { int b_ = bbase + (s); mSo[(s)&3] = binoff[b_]; mEo[(s)&3] = binoff[b_+1]; mIv[(s)&3] = inv[b_]; }
#define LDSRCS(s) { int so_ = mSo[(s)&3]; sA[(s)&1] = ssrc[so_]; sB[(s)&1] = ssrc[so_+1]; }
#define LDG(s) { const unsigned short* pa_ = G + (size_t)sA[(s)&1]*ROW + q8; \
                 const unsigned short* pb_ = G + (size_t)sB[(s)&1]*ROW + q8; \
                 _Pragma("unroll") for (int ks_ = 0; ks_ < KT; ++ks_) { \
                     g0[ks_] = *(const us8v*)(pa_ + ks_*32); \
                     g1[ks_] = *(const us8v*)(pb_ + ks_*32); } }

    // prologue
    LDMETA(0)
    if (RG > 1) LDMETA(1)
    if (RG > 2) LDMETA(2)
    LDSRCS(0)
    if (RG > 1) LDSRCS(1)
    LDG(0)

    // B fragments for it=0
    bf8v bfr[2][KT];
#pragma unroll
    for (int ct = 0; ct < 2; ++ct) {
        const int n = cb + 16 * ct + m16;
#pragma unroll
        for (int ks = 0; ks < KT; ++ks)
            bfr[ct][ks] = *(const bf8v*)(Bw + ((size_t)r0 * HID + n) * ROW + ks * 32 + q8);
    }

    f4v acc[2];
    acc[0] = f4v{0.f, 0.f, 0.f, 0.f};
    acc[1] = f4v{0.f, 0.f, 0.f, 0.f};

#pragma unroll
    for (int it = 0; it < RG; ++it) {
        const int so = mSo[it & 3], eo = mEo[it & 3];
        const int cnt = eo - so;
        const float iv = mIv[it & 3];

        // consume staged G-rows into fp32 accumulators (frees g0/g1)
        float a[KT][8];
#pragma unroll
        for (int ks = 0; ks < KT; ++ks)
#pragma unroll
            for (int k = 0; k < 8; ++k)
                a[ks][k] = b2f(g0[ks][k]) + (cnt >= 2 ? b2f(g1[ks][k]) : 0.0f);

        // issue next iteration's G-rows ASAP (full-iteration landing window)
        if (it + 1 < RG) LDG(it + 1)

        // rare tail: edges 2..cnt-1 (inline, exec-masked)
        for (int p = so + 2; p < eo; ++p) {
            const unsigned short* gp = G + (size_t)ssrc[p] * ROW + q8;
#pragma unroll
            for (int ks = 0; ks < KT; ++ks) {
                us8v g = *(const us8v*)(gp + ks * 32);
#pragma unroll
                for (int k = 0; k < 8; ++k) a[ks][k] += b2f(g[k]);
            }
        }

        // scale by inv (iv==0 for empty bin -> af==0) and pack to bf16 frags
        bf8v af[KT];
#pragma unroll
        for (int ks = 0; ks < KT; ++ks) {
            us8v t;
#pragma unroll
            for (int k = 0; k < 8; ++k) t[k] = f2b(a[ks][k] * iv);
            af[ks] = __builtin_bit_cast(bf8v, t);
        }

        // MFMA
#pragma unroll
        for (int ks = 0; ks < KT; ++ks) {
            acc[0] = __builtin_amdgcn_mfma_f32_16x16x32_bf16(af[ks], bfr[0][ks], acc[0], 0, 0, 0);
            acc[1] = __builtin_amdgcn_mfma_f32_16x16x32_bf16(af[ks], bfr[1][ks], acc[1], 0, 0, 0);
        }

        // advance the pipeline
        if (it + 2 < RG) LDSRCS(it + 2)
        if (it + 3 < RG) LDMETA(it + 3)

        // B fragments for it+1 (root weights after the last relation of last group)
        const unsigned short* Bp = (it + 1 < RG) ? (Bw + (size_t)(r0 + it + 1) * HID * ROW)
                                                 : (isLast ? Br : nullptr);
        if (Bp) {
#pragma unroll
            for (int ct = 0; ct < 2; ++ct) {
                const int n = cb + 16 * ct + m16;
#pragma unroll
                for (int ks = 0; ks < KT; ++ks)
                    bfr[ct][ks] = *(const bf8v*)(Bp + (size_t)n * ROW + ks * 32 + q8);
            }
        }
    }

    // root transform (last group only): A-fragments straight from own row
    if (isLast) {
        const unsigned short* gp = G + (size_t)grow * ROW + q8;
#pragma unroll
        for (int ks = 0; ks < KT; ++ks) {
            bf8v af = *(const bf8v*)(gp + ks * 32);
            acc[0] = __builtin_amdgcn_mfma_f32_16x16x32_bf16(af, bfr[0][ks], acc[0], 0, 0, 0);
            acc[1] = __builtin_amdgcn_mfma_f32_16x16x32_bf16(af, bfr[1][ks], acc[1], 0, 0, 0);
        }
    }

    // epilogue: fp32 partial, direct stores (C/D: row = q*4+g, col = 16*ct+m16)
    float* pb = part + (size_t)blockIdx.y * N_NODES * HID;
#pragma unroll
    for (int ct = 0; ct < 2; ++ct) {
        const int col = cb + 16 * ct + m16;
#pragma unroll
        for (int g = 0; g < 4; ++g) {
            const int row = d0 + rtb + q * 4 + g;
            pb[(size_t)row * HID + col] = acc[ct][g];
        }
    }
#undef LDMETA
#undef LDSRCS
#undef LDG
}

// ======== reduces (4 partials each) ========
__global__ __launch_bounds__(256) void reduce1_k(
    const float* __restrict__ part, const float* __restrict__ b1,
    unsigned short* __restrict__ h1b) {
    int i = blockIdx.x * 256 + threadIdx.x;   // float4 index
    if (i >= N_NODES * HID / 4) return;
    const size_t S = (size_t)N_NODES * HID;
    float4 r = *(const float4*)(b1 + ((i * 4) & 127));
#pragma unroll
    for (int p = 0; p < 4; ++p) {
        float4 a = ((const float4*)(part + p * S))[i];
        r.x += a.x; r.y += a.y; r.z += a.z; r.w += a.w;
    }
    us4v v;
    v[0] = f2b(fmaxf(r.x, 0.0f));
    v[1] = f2b(fmaxf(r.y, 0.0f));
    v[2] = f2b(fmaxf(r.z, 0.0f));
    v[3] = f2b(fmaxf(r.w, 0.0f));
    *(us4v*)(h1b + (size_t)i * 4) = v;
}

__global__ __launch_bounds__(256) void reduce2_k(
    const float* __restrict__ part, const float* __restrict__ b2,
    float* __restrict__ out) {
    int i = blockIdx.x * 256 + threadIdx.x;   // float4 index
    if (i >= N_NODES * HID / 4) return;
    const size_t S = (size_t)N_NODES * HID;
    float4 r = *(const float4*)(b2 + ((i * 4) & 127));
#pragma unroll
    for (int p = 0; p < 4; ++p) {
        float4 a = ((const float4*)(part + p * S))[i];
        r.x += a.x; r.y += a.y; r.z += a.z; r.w += a.w;
    }
    ((float4*)out)[i] = r;
}

extern "C" void kernel_launch(void* const* d_in, const int* in_sizes, int n_in,
                              void* d_out, int out_size, void* d_ws, size_t ws_size,
                              hipStream_t stream) {
    const int*   ei    = (const int*)d_in[0];   // [2, E]
    const int*   et    = (const int*)d_in[1];   // [E]
    const float* x     = (const float*)d_in[2]; // [N, 16]
    const float* W1    = (const float*)d_in[3]; // [32, 16, 128]
    const float* root1 = (const float*)d_in[4]; // [16, 128]
    const float* b1    = (const float*)d_in[5]; // [128]
    const float* W2    = (const float*)d_in[6]; // [32, 128, 128]
    const float* root2 = (const float*)d_in[7]; // [128, 128]
    const float* b2    = (const float*)d_in[8]; // [128]
    float* out = (float*)d_out;

    // ---- workspace layout (~60 MB) ----
    char* ws = (char*)d_ws;
    size_t off = 0;
    auto alloc = [&](size_t bytes) { void* p = ws + off; off = (off + bytes + 63) & ~(size_t)63; return p; };
    int*   hist    = (int*)  alloc((size_t)NB * 4);
    int*   binoff  = (int*)  alloc((size_t)(NB + 1) * 4);
    int*   cursors = (int*)  alloc((size_t)NB * 4);
    float* inv     = (float*)alloc((size_t)NB * 4);
    int*   bsum    = (int*)  alloc(625 * 4);
    int*   bbase   = (int*)  alloc(625 * 4);
    int*   ssrc    = (int*)  alloc((size_t)(N_EDGES + 2) * 4);
    unsigned short* xb  = (unsigned short*)alloc((size_t)N_NODES * 32 * 2);
    unsigned short* h1b = (unsigned short*)alloc((size_t)N_NODES * HID * 2);
    unsigned short* w1t = (unsigned short*)alloc((size_t)N_REL * HID * 32 * 2);
    unsigned short* r1t = (unsigned short*)alloc((size_t)HID * 32 * 2);
    unsigned short* w2t = (unsigned short*)alloc((size_t)N_REL * HID * HID * 2);
    unsigned short* r2t = (unsigned short*)alloc((size_t)HID * HID * 2);
    float* part = (float*)alloc((size_t)4 * N_NODES * HID * 4);   // 4 partials, reused both layers

    const int* src = ei;
    const int* dst = ei + N_EDGES;

    hipMemsetAsync(hist, 0, (size_t)NB * 4, stream);
    pre1_k<<<(PRE_TOT + 255) / 256, 256, 0, stream>>>(
        dst, et, x, W1, root1, W2, root2, hist, xb, w1t, r1t, w2t, r2t);
    scan1_k<<<NB / 1024, 256, 0, stream>>>(hist, binoff, bsum, inv);
    scan2_k<<<1, 1024, 0, stream>>>(bsum, bbase);
    scan3_k<<<(NB + 255) / 256, 256, 0, stream>>>(binoff, bbase, cursors);
    scatter_k<<<(N_EDGES + 255) / 256, 256, 0, stream>>>(src, dst, et, cursors, ssrc);

    // ---- layer 1: 4 relation groups (8 rels each; last adds root) ----
    gemm_w<1, 8><<<dim3(5000, 4), 64, 0, stream>>>(
        binoff, inv, ssrc, xb, w1t, r1t, part);
    reduce1_k<<<(N_NODES * HID / 4 + 255) / 256, 256, 0, stream>>>(part, b1, h1b);

    // ---- layer 2: 4 relation groups (8 rels each; last adds root) ----
    gemm_w<4, 8><<<dim3(5000, 4), 64, 0, stream>>>(
        binoff, inv, ssrc, h1b, w2t, r2t, part);
    reduce2_k<<<(N_NODES * HID / 4 + 255) / 256, 256, 0, stream>>>(part, b2, out);
}

// Round 13
// 496.824 us; speedup vs baseline: 1.2039x; 1.2039x over previous
//
#include <hip/hip_runtime.h>
#include <hip/hip_bf16.h>

#define N_NODES 20000
#define N_REL 32
#define HID 128
#define EMB 16
#define N_EDGES 600000
#define NB (N_NODES * N_REL)   // 640000 bins

typedef __attribute__((ext_vector_type(8))) short  bf8v;   // 8 bf16 (MFMA A/B frag)
typedef __attribute__((ext_vector_type(8))) unsigned short us8v; // 16-byte unit
typedef __attribute__((ext_vector_type(4))) float  f4v;    // MFMA C/D frag

__device__ __forceinline__ unsigned short f2b(float f) {
    __hip_bfloat16 h = __float2bfloat16(f);
    return __builtin_bit_cast(unsigned short, h);
}
__device__ __forceinline__ float b2f(unsigned short u) {
    unsigned int x = ((unsigned int)u) << 16;
    return __builtin_bit_cast(float, x);
}

// ======== pre-pass: histogram + all bf16 conversions/transposes ========
#define R_W2 (N_REL * HID * HID)        // 1048576
#define R_XB (N_NODES * 32)             // 640000
#define R_W1 (N_REL * HID * 32)         // 131072
#define R_R1 (HID * 32)                 // 4096
#define R_R2 (HID * HID)                // 16384
#define R_HIST N_EDGES                  // 600000
#define PRE_TOT (R_W2 + R_XB + R_W1 + R_R1 + R_R2 + R_HIST)

__global__ __launch_bounds__(256) void pre1_k(
    const int* __restrict__ dst, const int* __restrict__ et,
    const float* __restrict__ x, const float* __restrict__ W1,
    const float* __restrict__ root1, const float* __restrict__ W2,
    const float* __restrict__ root2,
    int* __restrict__ hist,
    unsigned short* __restrict__ xb, unsigned short* __restrict__ w1t,
    unsigned short* __restrict__ r1t, unsigned short* __restrict__ w2t,
    unsigned short* __restrict__ r2t) {
    int i = blockIdx.x * 256 + threadIdx.x;
    if (i < R_W2) {
        int r = i >> 14, k = (i >> 7) & 127, n = i & 127;
        w2t[(r << 14) + (n << 7) + k] = f2b(W2[i]);
        return;
    }
    i -= R_W2;
    if (i < R_XB) {
        int n = i >> 5, k = i & 31;
        xb[i] = (k < EMB) ? f2b(x[n * EMB + k]) : (unsigned short)0;
        return;
    }
    i -= R_XB;
    if (i < R_W1) {
        int r = i >> 12, n = (i >> 5) & 127, k = i & 31;
        w1t[i] = (k < EMB) ? f2b(W1[(r << 11) + (k << 7) + n]) : (unsigned short)0;
        return;
    }
    i -= R_W1;
    if (i < R_R1) {
        int n = i >> 5, k = i & 31;
        r1t[i] = (k < EMB) ? f2b(root1[(k << 7) + n]) : (unsigned short)0;
        return;
    }
    i -= R_R1;
    if (i < R_R2) {
        int n = i >> 7, k = i & 127;
        r2t[i] = f2b(root2[(k << 7) + n]);
        return;
    }
    i -= R_R2;
    if (i < R_HIST) atomicAdd(&hist[dst[i] * N_REL + et[i]], 1);
}

// ======== 2-level exclusive scan over NB = 625 x 1024 (+ inv fused) ========
__global__ void scan1_k(const int* __restrict__ hist, int* __restrict__ binoff,
                        int* __restrict__ bsum, float* __restrict__ inv) {
    __shared__ int sh[256];
    const int t = threadIdx.x;
    const int base = blockIdx.x * 1024 + t * 4;
    int4 h4 = *(const int4*)(hist + base);
    float4 iv4;
    iv4.x = h4.x > 0 ? 1.0f / h4.x : 0.0f;
    iv4.y = h4.y > 0 ? 1.0f / h4.y : 0.0f;
    iv4.z = h4.z > 0 ? 1.0f / h4.z : 0.0f;
    iv4.w = h4.w > 0 ? 1.0f / h4.w : 0.0f;
    *(float4*)(inv + base) = iv4;
    int ts = h4.x + h4.y + h4.z + h4.w;
    sh[t] = ts;
    __syncthreads();
    for (int o = 1; o < 256; o <<= 1) {
        int v = (t >= o) ? sh[t - o] : 0;
        __syncthreads();
        sh[t] += v;
        __syncthreads();
    }
    int exc = sh[t] - ts;
    binoff[base + 0] = exc;
    binoff[base + 1] = exc + h4.x;
    binoff[base + 2] = exc + h4.x + h4.y;
    binoff[base + 3] = exc + h4.x + h4.y + h4.z;
    if (t == 255) bsum[blockIdx.x] = sh[255];
}

__global__ void scan2_k(const int* __restrict__ bsum, int* __restrict__ bbase) {
    __shared__ int sh[1024];
    const int t = threadIdx.x;
    int v = (t < 625) ? bsum[t] : 0;
    sh[t] = v;
    __syncthreads();
    for (int o = 1; o < 1024; o <<= 1) {
        int u = (t >= o) ? sh[t - o] : 0;
        __syncthreads();
        sh[t] += u;
        __syncthreads();
    }
    if (t < 625) bbase[t] = sh[t] - v;
}

__global__ void scan3_k(int* __restrict__ binoff, const int* __restrict__ bbase,
                        int* __restrict__ cursors) {
    int i = blockIdx.x * 256 + threadIdx.x;
    if (i < NB) {
        int v = binoff[i] + bbase[i >> 10];
        binoff[i] = v;
        cursors[i] = v;
    }
    if (i == 0) binoff[NB] = N_EDGES;
}

__global__ void scatter_k(const int* __restrict__ src, const int* __restrict__ dst,
                          const int* __restrict__ et, int* __restrict__ cursors,
                          int* __restrict__ ssrc) {
    int e = blockIdx.x * 256 + threadIdx.x;
    if (e < 4) ssrc[N_EDGES + e] = 0;   // pad: safe src for speculative loads
    if (e < N_EDGES) {
        int b = dst[e] * N_REL + et[e];
        int p = atomicAdd(&cursors[b], 1);
        ssrc[p] = src[e];
    }
}

// ======== barrier-free wave-autonomous fused gather-GEMM ========
// 625 blocks x 128 thr. Wave w of a block: the SAME 32 rows (d0..d0+31, so the
// 2nd wave's gather hits L1), cols w*64..w*64+63 (4 col-tiles). Full K per
// wave: 32 relations + root -> DIRECT store (+bias, relu for L1). NO
// __syncthreads anywhere; a wave's s_waitcnt stalls only itself.
// Meta (binoff/inv, contiguous 8.2 KB) preloaded wave-privately to LDS.
// Edge pipeline (branch-free): srcs(it+2) issued at it; G-rows edges 0/1 for
// it+1 double-buffered (issued at it); edge 2 issued at start of it (mask
// cnt>=3); serial tail only for cnt>=4 (~1.6%/bin).
template<int KT, bool L1OUT>
__global__ __launch_bounds__(128) void gemm_a(
    const int* __restrict__ binoff, const float* __restrict__ inv,
    const int* __restrict__ ssrc,
    const unsigned short* __restrict__ G,    // bf16 rows [*, KT*32]
    const unsigned short* __restrict__ Bw,   // bf16 W^T [r][128][KT*32]
    const unsigned short* __restrict__ Br,   // bf16 root^T [128][KT*32]
    const float* __restrict__ bias,
    void* __restrict__ outp) {

    constexpr int ROW = KT * 32;

    const int tid = threadIdx.x;
    const int w = tid >> 6, lane = tid & 63;
    const int q = lane >> 4, m16 = lane & 15, q8 = q * 8;
    const int d0 = blockIdx.x * 32;
    const int cb = w * 64;

    // ---- wave-private meta preload (contiguous, coalesced) ----
    __shared__ int   sO[2][1025];
    __shared__ float sI[2][1024];
    for (int i = lane; i < 1025; i += 64) sO[w][i] = binoff[d0 * N_REL + i];
    for (int i = lane; i < 1024; i += 64) sI[w][i] = inv[d0 * N_REL + i];
    asm volatile("s_waitcnt lgkmcnt(0) vmcnt(0)");  // own-wave LDS visibility

    const int rl0 = m16, rl1 = 16 + m16;             // local rows (2 row-tiles)

    f4v acc[2][4];
#pragma unroll
    for (int rt = 0; rt < 2; ++rt)
#pragma unroll
        for (int ct = 0; ct < 4; ++ct) acc[rt][ct] = f4v{0.f, 0.f, 0.f, 0.f};

    float bc[4];
#pragma unroll
    for (int ct = 0; ct < 4; ++ct) bc[ct] = bias[cb + 16 * ct + m16];

    // ---- pipeline state ----
    int sc[2][3];                 // srcs (edges 0,1,2) for iteration `it`
    int sn[2][3];                 // srcs for iteration `it+1`
    us8v gA[2][2][KT], gB[2][2][KT];   // [buf][rt][ks] staged edges 0/1

    // prologue: srcs(0) -> G01(0, buf0); srcs(1)
#pragma unroll
    for (int rt = 0; rt < 2; ++rt) {
        const int rl = rt ? rl1 : rl0;
        int so = sO[w][rl * 32 + 0];
        sc[rt][0] = ssrc[so]; sc[rt][1] = ssrc[so + 1]; sc[rt][2] = ssrc[so + 2];
        int so1 = sO[w][rl * 32 + 1];
        sn[rt][0] = ssrc[so1]; sn[rt][1] = ssrc[so1 + 1]; sn[rt][2] = ssrc[so1 + 2];
    }
#pragma unroll
    for (int rt = 0; rt < 2; ++rt) {
        const unsigned short* pa = G + (size_t)sc[rt][0] * ROW + q8;
        const unsigned short* pb = G + (size_t)sc[rt][1] * ROW + q8;
#pragma unroll
        for (int ks = 0; ks < KT; ++ks) {
            gA[0][rt][ks] = *(const us8v*)(pa + ks * 32);
            gB[0][rt][ks] = *(const us8v*)(pb + ks * 32);
        }
    }

#pragma unroll 2
    for (int it = 0; it < N_REL; ++it) {
        const int buf = it & 1;

        // issue edge-2 rows for this iteration (mask applied at consume)
        us8v g2[2][KT];
#pragma unroll
        for (int rt = 0; rt < 2; ++rt) {
            const unsigned short* p2 = G + (size_t)sc[rt][2] * ROW + q8;
#pragma unroll
            for (int ks = 0; ks < KT; ++ks) g2[rt][ks] = *(const us8v*)(p2 + ks * 32);
        }

        // issue B(it) for all 4 col-tiles
        bf8v bf[4][KT];
        {
            const unsigned short* Bp = Bw + (size_t)it * HID * ROW;
#pragma unroll
            for (int ct = 0; ct < 4; ++ct) {
                const int n = cb + 16 * ct + m16;
#pragma unroll
                for (int ks = 0; ks < KT; ++ks)
                    bf[ct][ks] = *(const bf8v*)(Bp + (size_t)n * ROW + ks * 32 + q8);
            }
        }

        // consume staged edges -> A fragments (branch-free masks)
        bf8v af[2][KT];
#pragma unroll
        for (int rt = 0; rt < 2; ++rt) {
            const int rl = rt ? rl1 : rl0;
            const int so = sO[w][rl * 32 + it], eo = sO[w][rl * 32 + it + 1];
            const int cnt = eo - so;
            const float iv = sI[w][rl * 32 + it];
            const float m2 = cnt >= 2 ? 1.f : 0.f;
            const float m3 = cnt >= 3 ? 1.f : 0.f;
            float a[KT * 8];
#pragma unroll
            for (int ks = 0; ks < KT; ++ks)
#pragma unroll
                for (int k = 0; k < 8; ++k)
                    a[ks * 8 + k] = b2f(gA[buf][rt][ks][k])
                                  + m2 * b2f(gB[buf][rt][ks][k])
                                  + m3 * b2f(g2[rt][ks][k]);
            for (int p = so + 3; p < eo; ++p) {   // rare serial tail (cnt>=4)
                const unsigned short* gp = G + (size_t)ssrc[p] * ROW + q8;
#pragma unroll
                for (int ks = 0; ks < KT; ++ks) {
                    us8v g = *(const us8v*)(gp + ks * 32);
#pragma unroll
                    for (int k = 0; k < 8; ++k) a[ks * 8 + k] += b2f(g[k]);
                }
            }
#pragma unroll
            for (int ks = 0; ks < KT; ++ks) {
                us8v t;
#pragma unroll
                for (int k = 0; k < 8; ++k) t[k] = f2b(a[ks * 8 + k] * iv);
                af[rt][ks] = __builtin_bit_cast(bf8v, t);
            }
        }

        // refill: issue G01(it+1) into other buffer; rotate srcs; issue srcs(it+2)
        if (it + 1 < N_REL) {
#pragma unroll
            for (int rt = 0; rt < 2; ++rt) {
                const unsigned short* pa = G + (size_t)sn[rt][0] * ROW + q8;
                const unsigned short* pb = G + (size_t)sn[rt][1] * ROW + q8;
#pragma unroll
                for (int ks = 0; ks < KT; ++ks) {
                    gA[buf ^ 1][rt][ks] = *(const us8v*)(pa + ks * 32);
                    gB[buf ^ 1][rt][ks] = *(const us8v*)(pb + ks * 32);
                }
            }
#pragma unroll
            for (int rt = 0; rt < 2; ++rt) {
#pragma unroll
                for (int j = 0; j < 3; ++j) sc[rt][j] = sn[rt][j];
            }
            if (it + 2 < N_REL) {
#pragma unroll
                for (int rt = 0; rt < 2; ++rt) {
                    const int rl = rt ? rl1 : rl0;
                    int so2 = sO[w][rl * 32 + it + 2];
                    sn[rt][0] = ssrc[so2]; sn[rt][1] = ssrc[so2 + 1]; sn[rt][2] = ssrc[so2 + 2];
                }
            }
        }

        // MFMA: 2 rt x 4 ct x KT
#pragma unroll
        for (int ct = 0; ct < 4; ++ct)
#pragma unroll
            for (int rt = 0; rt < 2; ++rt)
#pragma unroll
                for (int ks = 0; ks < KT; ++ks)
                    acc[rt][ct] = __builtin_amdgcn_mfma_f32_16x16x32_bf16(
                        af[rt][ks], bf[ct][ks], acc[rt][ct], 0, 0, 0);
    }

    // ---- root transform: A = own rows, B = root^T ----
    {
        bf8v afr[2][KT];
#pragma unroll
        for (int rt = 0; rt < 2; ++rt) {
            const unsigned short* gp = G + (size_t)(d0 + (rt ? rl1 : rl0)) * ROW + q8;
#pragma unroll
            for (int ks = 0; ks < KT; ++ks) afr[rt][ks] = *(const bf8v*)(gp + ks * 32);
        }
#pragma unroll
        for (int ct = 0; ct < 4; ++ct) {
            const int n = cb + 16 * ct + m16;
#pragma unroll
            for (int ks = 0; ks < KT; ++ks) {
                bf8v bfr = *(const bf8v*)(Br + (size_t)n * ROW + ks * 32 + q8);
#pragma unroll
                for (int rt = 0; rt < 2; ++rt)
                    acc[rt][ct] = __builtin_amdgcn_mfma_f32_16x16x32_bf16(
                        afr[rt][ks], bfr, acc[rt][ct], 0, 0, 0);
            }
        }
    }

    // ---- epilogue: direct stores (C/D: row = 16*rt + q*4+g, col = cb+16ct+m16) ----
#pragma unroll
    for (int ct = 0; ct < 4; ++ct) {
        const int col = cb + 16 * ct + m16;
#pragma unroll
        for (int rt = 0; rt < 2; ++rt) {
#pragma unroll
            for (int g = 0; g < 4; ++g) {
                const size_t row = (size_t)(d0 + 16 * rt + q * 4 + g);
                const float v = acc[rt][ct][g] + bc[ct];
                if constexpr (L1OUT) {
                    ((unsigned short*)outp)[row * HID + col] = f2b(fmaxf(v, 0.0f));
                } else {
                    ((float*)outp)[row * HID + col] = v;
                }
            }
        }
    }
}

extern "C" void kernel_launch(void* const* d_in, const int* in_sizes, int n_in,
                              void* d_out, int out_size, void* d_ws, size_t ws_size,
                              hipStream_t stream) {
    const int*   ei    = (const int*)d_in[0];   // [2, E]
    const int*   et    = (const int*)d_in[1];   // [E]
    const float* x     = (const float*)d_in[2]; // [N, 16]
    const float* W1    = (const float*)d_in[3]; // [32, 16, 128]
    const float* root1 = (const float*)d_in[4]; // [16, 128]
    const float* b1    = (const float*)d_in[5]; // [128]
    const float* W2    = (const float*)d_in[6]; // [32, 128, 128]
    const float* root2 = (const float*)d_in[7]; // [128, 128]
    const float* b2    = (const float*)d_in[8]; // [128]
    float* out = (float*)d_out;

    // ---- workspace layout ----
    char* ws = (char*)d_ws;
    size_t off = 0;
    auto alloc = [&](size_t bytes) { void* p = ws + off; off = (off + bytes + 63) & ~(size_t)63; return p; };
    int*   hist    = (int*)  alloc((size_t)NB * 4);
    int*   binoff  = (int*)  alloc((size_t)(NB + 1) * 4);
    int*   cursors = (int*)  alloc((size_t)NB * 4);
    float* inv     = (float*)alloc((size_t)NB * 4);
    int*   bsum    = (int*)  alloc(625 * 4);
    int*   bbase   = (int*)  alloc(625 * 4);
    int*   ssrc    = (int*)  alloc((size_t)(N_EDGES + 4) * 4);
    unsigned short* xb  = (unsigned short*)alloc((size_t)N_NODES * 32 * 2);
    unsigned short* h1b = (unsigned short*)alloc((size_t)N_NODES * HID * 2);
    unsigned short* w1t = (unsigned short*)alloc((size_t)N_REL * HID * 32 * 2);
    unsigned short* r1t = (unsigned short*)alloc((size_t)HID * 32 * 2);
    unsigned short* w2t = (unsigned short*)alloc((size_t)N_REL * HID * HID * 2);
    unsigned short* r2t = (unsigned short*)alloc((size_t)HID * HID * 2);

    const int* src = ei;
    const int* dst = ei + N_EDGES;

    hipMemsetAsync(hist, 0, (size_t)NB * 4, stream);
    pre1_k<<<(PRE_TOT + 255) / 256, 256, 0, stream>>>(
        dst, et, x, W1, root1, W2, root2, hist, xb, w1t, r1t, w2t, r2t);
    scan1_k<<<NB / 1024, 256, 0, stream>>>(hist, binoff, bsum, inv);
    scan2_k<<<1, 1024, 0, stream>>>(bsum, bbase);
    scan3_k<<<(NB + 255) / 256, 256, 0, stream>>>(binoff, bbase, cursors);
    scatter_k<<<(N_EDGES + 255) / 256, 256, 0, stream>>>(src, dst, et, cursors, ssrc);

    // layer 1: direct h1b = bf16(relu(agg + x@root1 + b1))
    gemm_a<1, true><<<625, 128, 0, stream>>>(
        binoff, inv, ssrc, xb, w1t, r1t, b1, h1b);

    // layer 2: direct out = agg + relu(h1)@root2 + b2 (fp32)
    gemm_a<4, false><<<625, 128, 0, stream>>>(
        binoff, inv, ssrc, h1b, w2t, r2t, b2, out);
}

// Round 14
// 305.428 us; speedup vs baseline: 1.9583x; 1.6266x over previous
//
#include <hip/hip_runtime.h>
#include <hip/hip_bf16.h>

#define N_NODES 20000
#define N_REL 32
#define HID 128
#define EMB 16
#define N_EDGES 600000
#define NB (N_NODES * N_REL)   // 640000 bins

typedef __attribute__((ext_vector_type(8))) short  bf8v;   // 8 bf16 (MFMA A/B frag)
typedef __attribute__((ext_vector_type(8))) unsigned short us8v; // 16-byte unit
typedef __attribute__((ext_vector_type(4))) unsigned short us4v; // 8-byte unit
typedef __attribute__((ext_vector_type(4))) float  f4v;    // MFMA C/D frag

__device__ __forceinline__ unsigned short f2b(float f) {
    __hip_bfloat16 h = __float2bfloat16(f);
    return __builtin_bit_cast(unsigned short, h);
}
__device__ __forceinline__ float b2f(unsigned short u) {
    unsigned int x = ((unsigned int)u) << 16;
    return __builtin_bit_cast(float, x);
}

// Barrier with LDS-only drain: does NOT wait vmcnt, so in-flight global
// prefetches survive across it (their consumers get compiler-precise
// vmcnt(N) waits). Correct here because the only cross-wave communication
// is through LDS (ds_write/ds_read retire under lgkmcnt).
__device__ __forceinline__ void lds_barrier() {
    asm volatile("s_waitcnt lgkmcnt(0)\n\ts_barrier" ::: "memory");
}

// ======== pre-pass: histogram + all bf16 conversions/transposes ========
#define R_W2 (N_REL * HID * HID)        // 1048576
#define R_XB (N_NODES * 32)             // 640000
#define R_W1 (N_REL * HID * 32)         // 131072
#define R_R1 (HID * 32)                 // 4096
#define R_R2 (HID * HID)                // 16384
#define R_HIST N_EDGES                  // 600000
#define PRE_TOT (R_W2 + R_XB + R_W1 + R_R1 + R_R2 + R_HIST)

__global__ __launch_bounds__(256) void pre1_k(
    const int* __restrict__ dst, const int* __restrict__ et,
    const float* __restrict__ x, const float* __restrict__ W1,
    const float* __restrict__ root1, const float* __restrict__ W2,
    const float* __restrict__ root2,
    int* __restrict__ hist,
    unsigned short* __restrict__ xb, unsigned short* __restrict__ w1t,
    unsigned short* __restrict__ r1t, unsigned short* __restrict__ w2t,
    unsigned short* __restrict__ r2t) {
    int i = blockIdx.x * 256 + threadIdx.x;
    if (i < R_W2) {
        int r = i >> 14, k = (i >> 7) & 127, n = i & 127;
        w2t[(r << 14) + (n << 7) + k] = f2b(W2[i]);
        return;
    }
    i -= R_W2;
    if (i < R_XB) {
        int n = i >> 5, k = i & 31;
        xb[i] = (k < EMB) ? f2b(x[n * EMB + k]) : (unsigned short)0;
        return;
    }
    i -= R_XB;
    if (i < R_W1) {
        int r = i >> 12, n = (i >> 5) & 127, k = i & 31;
        w1t[i] = (k < EMB) ? f2b(W1[(r << 11) + (k << 7) + n]) : (unsigned short)0;
        return;
    }
    i -= R_W1;
    if (i < R_R1) {
        int n = i >> 5, k = i & 31;
        r1t[i] = (k < EMB) ? f2b(root1[(k << 7) + n]) : (unsigned short)0;
        return;
    }
    i -= R_R1;
    if (i < R_R2) {
        int n = i >> 7, k = i & 127;
        r2t[i] = f2b(root2[(k << 7) + n]);
        return;
    }
    i -= R_R2;
    if (i < R_HIST) atomicAdd(&hist[dst[i] * N_REL + et[i]], 1);
}

// ======== 2-level exclusive scan over NB = 625 x 1024 (+ inv fused) ========
__global__ void scan1_k(const int* __restrict__ hist, int* __restrict__ binoff,
                        int* __restrict__ bsum, float* __restrict__ inv) {
    __shared__ int sh[256];
    const int t = threadIdx.x;
    const int base = blockIdx.x * 1024 + t * 4;
    int4 h4 = *(const int4*)(hist + base);
    float4 iv4;
    iv4.x = h4.x > 0 ? 1.0f / h4.x : 0.0f;
    iv4.y = h4.y > 0 ? 1.0f / h4.y : 0.0f;
    iv4.z = h4.z > 0 ? 1.0f / h4.z : 0.0f;
    iv4.w = h4.w > 0 ? 1.0f / h4.w : 0.0f;
    *(float4*)(inv + base) = iv4;
    int ts = h4.x + h4.y + h4.z + h4.w;
    sh[t] = ts;
    __syncthreads();
    for (int o = 1; o < 256; o <<= 1) {
        int v = (t >= o) ? sh[t - o] : 0;
        __syncthreads();
        sh[t] += v;
        __syncthreads();
    }
    int exc = sh[t] - ts;
    binoff[base + 0] = exc;
    binoff[base + 1] = exc + h4.x;
    binoff[base + 2] = exc + h4.x + h4.y;
    binoff[base + 3] = exc + h4.x + h4.y + h4.z;
    if (t == 255) bsum[blockIdx.x] = sh[255];
}

__global__ void scan2_k(const int* __restrict__ bsum, int* __restrict__ bbase) {
    __shared__ int sh[1024];
    const int t = threadIdx.x;
    int v = (t < 625) ? bsum[t] : 0;
    sh[t] = v;
    __syncthreads();
    for (int o = 1; o < 1024; o <<= 1) {
        int u = (t >= o) ? sh[t - o] : 0;
        __syncthreads();
        sh[t] += u;
        __syncthreads();
    }
    if (t < 625) bbase[t] = sh[t] - v;
}

__global__ void scan3_k(int* __restrict__ binoff, const int* __restrict__ bbase,
                        int* __restrict__ cursors) {
    int i = blockIdx.x * 256 + threadIdx.x;
    if (i < NB) {
        int v = binoff[i] + bbase[i >> 10];
        binoff[i] = v;
        cursors[i] = v;
    }
    if (i == 0) binoff[NB] = N_EDGES;
}

__global__ void scatter_k(const int* __restrict__ src, const int* __restrict__ dst,
                          const int* __restrict__ et, int* __restrict__ cursors,
                          int* __restrict__ ssrc) {
    int e = blockIdx.x * 256 + threadIdx.x;
    if (e < 2) ssrc[N_EDGES + e] = 0;   // pad: safe src for speculative loads
    if (e < N_EDGES) {
        int b = dst[e] * N_REL + et[e];
        int p = atomicAdd(&cursors[b], 1);
        ssrc[p] = src[e];
    }
}

// ======== fused aggregate+transform, relation-split, fp32 partials ========
// R9 structure (best measured) with lds_barrier() replacing __syncthreads():
// the per-iteration barrier no longer drains vmcnt, so the 2-deep
// meta/ssrc/G prefetch pipeline actually stays in flight across it.
// grid (625, N_REL/RG). Block y handles relations [y*RG, y*RG+RG); last group
// also adds the root transform. Output: 32x128 fp32 partial at part+y*N*HID.
template<int KT, int LSS, int CW, int RG>
__global__ __launch_bounds__(256) void gemm_f(
    const int* __restrict__ binoff, const float* __restrict__ inv,
    const int* __restrict__ ssrc,
    const unsigned short* __restrict__ G,    // bf16 rows [*, KT*32]
    const unsigned short* __restrict__ Bw,   // bf16 W^T [r][128][KT*32]
    const unsigned short* __restrict__ Br,   // bf16 root^T [128][KT*32]
    float* __restrict__ part) {

    constexpr int ROW = KT * 32;
    constexpr int NCH = ROW / CW;
    constexpr int CP8 = CW / 8;
    static_assert(NCH * CW == ROW, "chunk covering must be exact");
    static_assert(32 * NCH <= 256, "one gather item per thread");

    __shared__ __align__(16) unsigned short As[2][32 * LSS];
    __shared__ int   smO[32 * (RG + 1)];
    __shared__ float smI[32 * RG];

    const int t = threadIdx.x;
    const int w = t >> 6, lane = t & 63;
    const int q = lane >> 4, m16 = lane & 15;
    const int d0 = blockIdx.x * 32;
    const int r0 = blockIdx.y * RG;
    const bool isLast = (blockIdx.y == gridDim.y - 1);
    const int colb = w * 32;
    const bool gat = t < 32 * NCH;
    const int grow = t / NCH, gcc = t % NCH;
    const int mb  = grow * (RG + 1);
    const int mbI = grow * RG;

    // ---- meta preload (this group's bins only) ----
    for (int i = t; i < 32 * (RG + 1); i += 256) {
        int row = i / (RG + 1), rr = i % (RG + 1);
        smO[i] = binoff[(d0 + row) * N_REL + r0 + rr];
    }
    for (int i = t; i < 32 * RG; i += 256) {
        int row = i / RG, rr = i % RG;
        smI[i] = inv[(d0 + row) * N_REL + r0 + rr];
    }
    lds_barrier();

    f4v acc[2][2];
#pragma unroll
    for (int rt = 0; rt < 2; ++rt)
#pragma unroll
        for (int ct = 0; ct < 2; ++ct) acc[rt][ct] = f4v{0.f, 0.f, 0.f, 0.f};

    // ---- prologue: prime the 2-deep edge pipeline for it=0 ----
    us8v gA[CP8], gB[CP8];
#pragma unroll
    for (int j = 0; j < CP8; ++j) { gA[j] = us8v{}; gB[j] = us8v{}; }
    int sx = 0, sy = 0;
    if (gat) {
        int so = smO[mb], cnt = smO[mb + 1] - so;
        if (cnt >= 1) sx = ssrc[so];
        if (cnt >= 2) sy = ssrc[so + 1];
        if (cnt >= 1) {
            const unsigned short* gp = G + (size_t)sx * ROW + gcc * CW;
#pragma unroll
            for (int j = 0; j < CP8; ++j) gA[j] = *(const us8v*)(gp + j * 8);
        }
        if (cnt >= 2) {
            const unsigned short* gp = G + (size_t)sy * ROW + gcc * CW;
#pragma unroll
            for (int j = 0; j < CP8; ++j) gB[j] = *(const us8v*)(gp + j * 8);
        }
        if (RG > 1) {
            int so1 = smO[mb + 1], c1 = smO[mb + 2] - so1;
            if (c1 >= 1) sx = ssrc[so1];
            if (c1 >= 2) sy = ssrc[so1 + 1];
        }
    }

    // B fragments for it=0
    bf8v bfr[2][KT];
#pragma unroll
    for (int ct = 0; ct < 2; ++ct) {
        const int n = colb + 16 * ct + m16;
#pragma unroll
        for (int ks = 0; ks < KT; ++ks)
            bfr[ct][ks] = *(const bf8v*)(Bw + ((size_t)r0 * HID + n) * ROW + ks * 32 + q * 8);
    }

    for (int it = 0; it < RG; ++it) {
        unsigned short* Ab = As[it & 1];
        // ---- gather (consumes gA/gB primed last iteration) ----
        if (gat) {
            const int so = smO[mb + it], eo = smO[mb + it + 1];
            const int cnt = eo - so;
            float a[CW];
#pragma unroll
            for (int j = 0; j < CW; ++j) a[j] = 0.f;
            if (cnt >= 1) {
#pragma unroll
                for (int j = 0; j < CP8; ++j)
#pragma unroll
                    for (int k = 0; k < 8; ++k) a[j * 8 + k] += b2f(gA[j][k]);
            }
            if (cnt >= 2) {
#pragma unroll
                for (int j = 0; j < CP8; ++j)
#pragma unroll
                    for (int k = 0; k < 8; ++k) a[j * 8 + k] += b2f(gB[j][k]);
            }
            for (int p = so + 2; p < eo; ++p) {     // rare tail (P ~6%)
                const unsigned short* gp = G + (size_t)ssrc[p] * ROW + gcc * CW;
#pragma unroll
                for (int j = 0; j < CP8; ++j) {
                    us8v g = *(const us8v*)(gp + j * 8);
#pragma unroll
                    for (int k = 0; k < 8; ++k) a[j * 8 + k] += b2f(g[k]);
                }
            }
            const float iv = smI[mbI + it];
            unsigned short* wp = &Ab[grow * LSS + gcc * CW];
#pragma unroll
            for (int j = 0; j < CP8; ++j) {
                us8v sv;
#pragma unroll
                for (int k = 0; k < 8; ++k) sv[k] = f2b(a[j * 8 + k] * iv);
                *(us8v*)(wp + j * 8) = sv;
            }
        }
        lds_barrier();   // LDS-only drain: global prefetches stay in flight

        // ---- post-barrier prefetch for it+1 / it+2 ----
        if (gat && it + 1 < RG) {
            const int c1 = smO[mb + it + 2] - smO[mb + it + 1];
            if (c1 >= 1) {
                const unsigned short* gp = G + (size_t)sx * ROW + gcc * CW;
#pragma unroll
                for (int j = 0; j < CP8; ++j) gA[j] = *(const us8v*)(gp + j * 8);
            }
            if (c1 >= 2) {
                const unsigned short* gp = G + (size_t)sy * ROW + gcc * CW;
#pragma unroll
                for (int j = 0; j < CP8; ++j) gB[j] = *(const us8v*)(gp + j * 8);
            }
            if (it + 2 < RG) {
                const int so2 = smO[mb + it + 2], c2 = smO[mb + it + 3] - so2;
                if (c2 >= 1) sx = ssrc[so2];
                if (c2 >= 2) sy = ssrc[so2 + 1];
            }
        }

        // ---- A fragments + MFMA ----
#pragma unroll
        for (int rt = 0; rt < 2; ++rt) {
            const unsigned short* ar = &Ab[(m16 + 16 * rt) * LSS];
#pragma unroll
            for (int ks = 0; ks < KT; ++ks) {
                bf8v af = *(const bf8v*)(ar + ks * 32 + q * 8);
                acc[rt][0] = __builtin_amdgcn_mfma_f32_16x16x32_bf16(af, bfr[0][ks], acc[rt][0], 0, 0, 0);
                acc[rt][1] = __builtin_amdgcn_mfma_f32_16x16x32_bf16(af, bfr[1][ks], acc[rt][1], 0, 0, 0);
            }
        }

        // ---- B fragments for it+1 (root weights after last relation of last group) ----
        const unsigned short* Bp = (it + 1 < RG) ? (Bw + (size_t)(r0 + it + 1) * HID * ROW)
                                                 : (isLast ? Br : nullptr);
        if (Bp) {
#pragma unroll
            for (int ct = 0; ct < 2; ++ct) {
                const int n = colb + 16 * ct + m16;
#pragma unroll
                for (int ks = 0; ks < KT; ++ks)
                    bfr[ct][ks] = *(const bf8v*)(Bp + (size_t)n * ROW + ks * 32 + q * 8);
            }
        }
    }

    // ---- root transform (last group only): A straight from global ----
    if (isLast) {
#pragma unroll
        for (int rt = 0; rt < 2; ++rt) {
#pragma unroll
            for (int ks = 0; ks < KT; ++ks) {
                bf8v af = *(const bf8v*)(G + (size_t)(d0 + m16 + 16 * rt) * ROW + ks * 32 + q * 8);
                acc[rt][0] = __builtin_amdgcn_mfma_f32_16x16x32_bf16(af, bfr[0][ks], acc[rt][0], 0, 0, 0);
                acc[rt][1] = __builtin_amdgcn_mfma_f32_16x16x32_bf16(af, bfr[1][ks], acc[rt][1], 0, 0, 0);
            }
        }
    }

    // ---- epilogue: direct fp32 partial stores ----
    float* pb = part + (size_t)blockIdx.y * N_NODES * HID;
#pragma unroll
    for (int ct = 0; ct < 2; ++ct) {
        const int col = colb + 16 * ct + m16;
#pragma unroll
        for (int rt = 0; rt < 2; ++rt) {
#pragma unroll
            for (int g = 0; g < 4; ++g) {
                const int rr = 16 * rt + q * 4 + g;
                pb[(size_t)(d0 + rr) * HID + col] = acc[rt][ct][g];
            }
        }
    }
}

// ======== reduces ========
__global__ __launch_bounds__(256) void reduce1_k(
    const float* __restrict__ part, const float* __restrict__ b1,
    unsigned short* __restrict__ h1b) {
    int i = blockIdx.x * 256 + threadIdx.x;   // float4 index
    if (i >= N_NODES * HID / 4) return;
    const size_t S = (size_t)N_NODES * HID;
    float4 a = ((const float4*)part)[i];
    float4 b = ((const float4*)(part + S))[i];
    float4 bb = *(const float4*)(b1 + ((i * 4) & 127));
    us4v v;
    v[0] = f2b(fmaxf(a.x + b.x + bb.x, 0.0f));
    v[1] = f2b(fmaxf(a.y + b.y + bb.y, 0.0f));
    v[2] = f2b(fmaxf(a.z + b.z + bb.z, 0.0f));
    v[3] = f2b(fmaxf(a.w + b.w + bb.w, 0.0f));
    *(us4v*)(h1b + (size_t)i * 4) = v;
}

__global__ __launch_bounds__(256) void reduce2_k(
    const float* __restrict__ part, const float* __restrict__ b2,
    float* __restrict__ out) {
    int i = blockIdx.x * 256 + threadIdx.x;   // float4 index
    if (i >= N_NODES * HID / 4) return;
    const size_t S = (size_t)N_NODES * HID;
    float4 a0 = ((const float4*)part)[i];
    float4 a1 = ((const float4*)(part + S))[i];
    float4 a2 = ((const float4*)(part + 2 * S))[i];
    float4 a3 = ((const float4*)(part + 3 * S))[i];
    float4 bb = *(const float4*)(b2 + ((i * 4) & 127));
    float4 r;
    r.x = (a0.x + a1.x) + (a2.x + a3.x) + bb.x;
    r.y = (a0.y + a1.y) + (a2.y + a3.y) + bb.y;
    r.z = (a0.z + a1.z) + (a2.z + a3.z) + bb.z;
    r.w = (a0.w + a1.w) + (a2.w + a3.w) + bb.w;
    ((float4*)out)[i] = r;
}

extern "C" void kernel_launch(void* const* d_in, const int* in_sizes, int n_in,
                              void* d_out, int out_size, void* d_ws, size_t ws_size,
                              hipStream_t stream) {
    const int*   ei    = (const int*)d_in[0];   // [2, E]
    const int*   et    = (const int*)d_in[1];   // [E]
    const float* x     = (const float*)d_in[2]; // [N, 16]
    const float* W1    = (const float*)d_in[3]; // [32, 16, 128]
    const float* root1 = (const float*)d_in[4]; // [16, 128]
    const float* b1    = (const float*)d_in[5]; // [128]
    const float* W2    = (const float*)d_in[6]; // [32, 128, 128]
    const float* root2 = (const float*)d_in[7]; // [128, 128]
    const float* b2    = (const float*)d_in[8]; // [128]
    float* out = (float*)d_out;

    // ---- workspace layout (~60 MB) ----
    char* ws = (char*)d_ws;
    size_t off = 0;
    auto alloc = [&](size_t bytes) { void* p = ws + off; off = (off + bytes + 63) & ~(size_t)63; return p; };
    int*   hist    = (int*)  alloc((size_t)NB * 4);
    int*   binoff  = (int*)  alloc((size_t)(NB + 1) * 4);
    int*   cursors = (int*)  alloc((size_t)NB * 4);
    float* inv     = (float*)alloc((size_t)NB * 4);
    int*   bsum    = (int*)  alloc(625 * 4);
    int*   bbase   = (int*)  alloc(625 * 4);
    int*   ssrc    = (int*)  alloc((size_t)(N_EDGES + 2) * 4);
    unsigned short* xb  = (unsigned short*)alloc((size_t)N_NODES * 32 * 2);
    unsigned short* h1b = (unsigned short*)alloc((size_t)N_NODES * HID * 2);
    unsigned short* w1t = (unsigned short*)alloc((size_t)N_REL * HID * 32 * 2);
    unsigned short* r1t = (unsigned short*)alloc((size_t)HID * 32 * 2);
    unsigned short* w2t = (unsigned short*)alloc((size_t)N_REL * HID * HID * 2);
    unsigned short* r2t = (unsigned short*)alloc((size_t)HID * HID * 2);
    float* part = (float*)alloc((size_t)4 * N_NODES * HID * 4);   // 4 partials, reused both layers

    const int* src = ei;
    const int* dst = ei + N_EDGES;

    hipMemsetAsync(hist, 0, (size_t)NB * 4, stream);
    pre1_k<<<(PRE_TOT + 255) / 256, 256, 0, stream>>>(
        dst, et, x, W1, root1, W2, root2, hist, xb, w1t, r1t, w2t, r2t);
    scan1_k<<<NB / 1024, 256, 0, stream>>>(hist, binoff, bsum, inv);
    scan2_k<<<1, 1024, 0, stream>>>(bsum, bbase);
    scan3_k<<<(NB + 255) / 256, 256, 0, stream>>>(binoff, bbase, cursors);
    scatter_k<<<(N_EDGES + 255) / 256, 256, 0, stream>>>(src, dst, et, cursors, ssrc);

    // ---- layer 1: 2 relation groups (16 rels each; last adds root) ----
    gemm_f<1, 40, 8, 16><<<dim3(625, 2), 256, 0, stream>>>(
        binoff, inv, ssrc, xb, w1t, r1t, part);
    reduce1_k<<<(N_NODES * HID / 4 + 255) / 256, 256, 0, stream>>>(part, b1, h1b);

    // ---- layer 2: 4 relation groups (8 rels each; last adds root) ----
    gemm_f<4, 136, 16, 8><<<dim3(625, 4), 256, 0, stream>>>(
        binoff, inv, ssrc, h1b, w2t, r2t, part);
    reduce2_k<<<(N_NODES * HID / 4 + 255) / 256, 256, 0, stream>>>(part, b2, out);
}

// Round 15
// 303.797 us; speedup vs baseline: 1.9688x; 1.0054x over previous
//
#include <hip/hip_runtime.h>
#include <hip/hip_bf16.h>

#define N_NODES 20000
#define N_REL 32
#define HID 128
#define EMB 16
#define N_EDGES 600000
#define NB (N_NODES * N_REL)   // 640000 bins

typedef __attribute__((ext_vector_type(8))) short  bf8v;   // 8 bf16 (MFMA A/B frag)
typedef __attribute__((ext_vector_type(8))) unsigned short us8v; // 16-byte unit
typedef __attribute__((ext_vector_type(4))) unsigned short us4v; // 8-byte unit
typedef __attribute__((ext_vector_type(4))) float  f4v;    // MFMA C/D frag

__device__ __forceinline__ unsigned short f2b(float f) {
    __hip_bfloat16 h = __float2bfloat16(f);
    return __builtin_bit_cast(unsigned short, h);
}
__device__ __forceinline__ float b2f(unsigned short u) {
    unsigned int x = ((unsigned int)u) << 16;
    return __builtin_bit_cast(float, x);
}

// Barrier with LDS-only drain (global prefetches stay in flight).
__device__ __forceinline__ void lds_barrier() {
    asm volatile("s_waitcnt lgkmcnt(0)\n\ts_barrier" ::: "memory");
}

// ======== pre-pass: histogram + all bf16 conversions/transposes ========
#define R_W2 (N_REL * HID * HID)        // 1048576
#define R_XB (N_NODES * 32)             // 640000
#define R_W1 (N_REL * HID * 32)         // 131072
#define R_R1 (HID * 32)                 // 4096
#define R_R2 (HID * HID)                // 16384
#define R_HIST N_EDGES                  // 600000
#define PRE_TOT (R_W2 + R_XB + R_W1 + R_R1 + R_R2 + R_HIST)

__global__ __launch_bounds__(256) void pre1_k(
    const int* __restrict__ dst, const int* __restrict__ et,
    const float* __restrict__ x, const float* __restrict__ W1,
    const float* __restrict__ root1, const float* __restrict__ W2,
    const float* __restrict__ root2,
    int* __restrict__ hist,
    unsigned short* __restrict__ xb, unsigned short* __restrict__ w1t,
    unsigned short* __restrict__ r1t, unsigned short* __restrict__ w2t,
    unsigned short* __restrict__ r2t) {
    int i = blockIdx.x * 256 + threadIdx.x;
    if (i < R_W2) {
        int r = i >> 14, k = (i >> 7) & 127, n = i & 127;
        w2t[(r << 14) + (n << 7) + k] = f2b(W2[i]);
        return;
    }
    i -= R_W2;
    if (i < R_XB) {
        int n = i >> 5, k = i & 31;
        xb[i] = (k < EMB) ? f2b(x[n * EMB + k]) : (unsigned short)0;
        return;
    }
    i -= R_XB;
    if (i < R_W1) {
        int r = i >> 12, n = (i >> 5) & 127, k = i & 31;
        w1t[i] = (k < EMB) ? f2b(W1[(r << 11) + (k << 7) + n]) : (unsigned short)0;
        return;
    }
    i -= R_W1;
    if (i < R_R1) {
        int n = i >> 5, k = i & 31;
        r1t[i] = (k < EMB) ? f2b(root1[(k << 7) + n]) : (unsigned short)0;
        return;
    }
    i -= R_R1;
    if (i < R_R2) {
        int n = i >> 7, k = i & 127;
        r2t[i] = f2b(root2[(k << 7) + n]);
        return;
    }
    i -= R_R2;
    if (i < R_HIST) atomicAdd(&hist[dst[i] * N_REL + et[i]], 1);
}

// ======== 2-level exclusive scan over NB = 625 x 1024 (+ inv fused) ========
__global__ void scan1_k(const int* __restrict__ hist, int* __restrict__ binoff,
                        int* __restrict__ bsum, float* __restrict__ inv) {
    __shared__ int sh[256];
    const int t = threadIdx.x;
    const int base = blockIdx.x * 1024 + t * 4;
    int4 h4 = *(const int4*)(hist + base);
    float4 iv4;
    iv4.x = h4.x > 0 ? 1.0f / h4.x : 0.0f;
    iv4.y = h4.y > 0 ? 1.0f / h4.y : 0.0f;
    iv4.z = h4.z > 0 ? 1.0f / h4.z : 0.0f;
    iv4.w = h4.w > 0 ? 1.0f / h4.w : 0.0f;
    *(float4*)(inv + base) = iv4;
    int ts = h4.x + h4.y + h4.z + h4.w;
    sh[t] = ts;
    __syncthreads();
    for (int o = 1; o < 256; o <<= 1) {
        int v = (t >= o) ? sh[t - o] : 0;
        __syncthreads();
        sh[t] += v;
        __syncthreads();
    }
    int exc = sh[t] - ts;
    binoff[base + 0] = exc;
    binoff[base + 1] = exc + h4.x;
    binoff[base + 2] = exc + h4.x + h4.y;
    binoff[base + 3] = exc + h4.x + h4.y + h4.z;
    if (t == 255) bsum[blockIdx.x] = sh[255];
}

__global__ void scan2_k(const int* __restrict__ bsum, int* __restrict__ bbase) {
    __shared__ int sh[1024];
    const int t = threadIdx.x;
    int v = (t < 625) ? bsum[t] : 0;
    sh[t] = v;
    __syncthreads();
    for (int o = 1; o < 1024; o <<= 1) {
        int u = (t >= o) ? sh[t - o] : 0;
        __syncthreads();
        sh[t] += u;
        __syncthreads();
    }
    if (t < 625) bbase[t] = sh[t] - v;
}

__global__ void scan3_k(int* __restrict__ binoff, const int* __restrict__ bbase,
                        int* __restrict__ cursors) {
    int i = blockIdx.x * 256 + threadIdx.x;
    if (i < NB) {
        int v = binoff[i] + bbase[i >> 10];
        binoff[i] = v;
        cursors[i] = v;
    }
    if (i == 0) binoff[NB] = N_EDGES;
}

__global__ void scatter_k(const int* __restrict__ src, const int* __restrict__ dst,
                          const int* __restrict__ et, int* __restrict__ cursors,
                          int* __restrict__ ssrc) {
    int e = blockIdx.x * 256 + threadIdx.x;
    if (e < 2) ssrc[N_EDGES + e] = 0;   // pad: safe src for speculative loads
    if (e < N_EDGES) {
        int b = dst[e] * N_REL + et[e];
        int p = atomicAdd(&cursors[b], 1);
        ssrc[p] = src[e];
    }
}

// ======== fused aggregate+transform, relation-split, fp32 partials ========
// R9/R13 structure; epilogue partial stores are NONTEMPORAL so the 40 MB
// write stream doesn't evict the L2-resident G rows / B weights (the R13
// counters showed 65 MB HBM FETCH on an L2-sized read set -> write-induced
// eviction was inflating G-load latency to HBM levels).
template<int KT, int LSS, int CW, int RG>
__global__ __launch_bounds__(256) void gemm_f(
    const int* __restrict__ binoff, const float* __restrict__ inv,
    const int* __restrict__ ssrc,
    const unsigned short* __restrict__ G,    // bf16 rows [*, KT*32]
    const unsigned short* __restrict__ Bw,   // bf16 W^T [r][128][KT*32]
    const unsigned short* __restrict__ Br,   // bf16 root^T [128][KT*32]
    float* __restrict__ part) {

    constexpr int ROW = KT * 32;
    constexpr int NCH = ROW / CW;
    constexpr int CP8 = CW / 8;
    static_assert(NCH * CW == ROW, "chunk covering must be exact");
    static_assert(32 * NCH <= 256, "one gather item per thread");

    __shared__ __align__(16) unsigned short As[2][32 * LSS];
    __shared__ int   smO[32 * (RG + 1)];
    __shared__ float smI[32 * RG];

    const int t = threadIdx.x;
    const int w = t >> 6, lane = t & 63;
    const int q = lane >> 4, m16 = lane & 15;
    const int d0 = blockIdx.x * 32;
    const int r0 = blockIdx.y * RG;
    const bool isLast = (blockIdx.y == gridDim.y - 1);
    const int colb = w * 32;
    const bool gat = t < 32 * NCH;
    const int grow = t / NCH, gcc = t % NCH;
    const int mb  = grow * (RG + 1);
    const int mbI = grow * RG;

    // ---- meta preload (this group's bins only) ----
    for (int i = t; i < 32 * (RG + 1); i += 256) {
        int row = i / (RG + 1), rr = i % (RG + 1);
        smO[i] = binoff[(d0 + row) * N_REL + r0 + rr];
    }
    for (int i = t; i < 32 * RG; i += 256) {
        int row = i / RG, rr = i % RG;
        smI[i] = inv[(d0 + row) * N_REL + r0 + rr];
    }
    lds_barrier();

    f4v acc[2][2];
#pragma unroll
    for (int rt = 0; rt < 2; ++rt)
#pragma unroll
        for (int ct = 0; ct < 2; ++ct) acc[rt][ct] = f4v{0.f, 0.f, 0.f, 0.f};

    // ---- prologue: prime the 2-deep edge pipeline for it=0 ----
    us8v gA[CP8], gB[CP8];
#pragma unroll
    for (int j = 0; j < CP8; ++j) { gA[j] = us8v{}; gB[j] = us8v{}; }
    int sx = 0, sy = 0;
    if (gat) {
        int so = smO[mb], cnt = smO[mb + 1] - so;
        if (cnt >= 1) sx = ssrc[so];
        if (cnt >= 2) sy = ssrc[so + 1];
        if (cnt >= 1) {
            const unsigned short* gp = G + (size_t)sx * ROW + gcc * CW;
#pragma unroll
            for (int j = 0; j < CP8; ++j) gA[j] = *(const us8v*)(gp + j * 8);
        }
        if (cnt >= 2) {
            const unsigned short* gp = G + (size_t)sy * ROW + gcc * CW;
#pragma unroll
            for (int j = 0; j < CP8; ++j) gB[j] = *(const us8v*)(gp + j * 8);
        }
        if (RG > 1) {
            int so1 = smO[mb + 1], c1 = smO[mb + 2] - so1;
            if (c1 >= 1) sx = ssrc[so1];
            if (c1 >= 2) sy = ssrc[so1 + 1];
        }
    }

    // B fragments for it=0
    bf8v bfr[2][KT];
#pragma unroll
    for (int ct = 0; ct < 2; ++ct) {
        const int n = colb + 16 * ct + m16;
#pragma unroll
        for (int ks = 0; ks < KT; ++ks)
            bfr[ct][ks] = *(const bf8v*)(Bw + ((size_t)r0 * HID + n) * ROW + ks * 32 + q * 8);
    }

    for (int it = 0; it < RG; ++it) {
        unsigned short* Ab = As[it & 1];
        // ---- gather (consumes gA/gB primed last iteration) ----
        if (gat) {
            const int so = smO[mb + it], eo = smO[mb + it + 1];
            const int cnt = eo - so;
            float a[CW];
#pragma unroll
            for (int j = 0; j < CW; ++j) a[j] = 0.f;
            if (cnt >= 1) {
#pragma unroll
                for (int j = 0; j < CP8; ++j)
#pragma unroll
                    for (int k = 0; k < 8; ++k) a[j * 8 + k] += b2f(gA[j][k]);
            }
            if (cnt >= 2) {
#pragma unroll
                for (int j = 0; j < CP8; ++j)
#pragma unroll
                    for (int k = 0; k < 8; ++k) a[j * 8 + k] += b2f(gB[j][k]);
            }
            for (int p = so + 2; p < eo; ++p) {     // rare tail (P ~6%)
                const unsigned short* gp = G + (size_t)ssrc[p] * ROW + gcc * CW;
#pragma unroll
                for (int j = 0; j < CP8; ++j) {
                    us8v g = *(const us8v*)(gp + j * 8);
#pragma unroll
                    for (int k = 0; k < 8; ++k) a[j * 8 + k] += b2f(g[k]);
                }
            }
            const float iv = smI[mbI + it];
            unsigned short* wp = &Ab[grow * LSS + gcc * CW];
#pragma unroll
            for (int j = 0; j < CP8; ++j) {
                us8v sv;
#pragma unroll
                for (int k = 0; k < 8; ++k) sv[k] = f2b(a[j * 8 + k] * iv);
                *(us8v*)(wp + j * 8) = sv;
            }
        }
        lds_barrier();   // LDS-only drain: global prefetches stay in flight

        // ---- post-barrier prefetch for it+1 / it+2 ----
        if (gat && it + 1 < RG) {
            const int c1 = smO[mb + it + 2] - smO[mb + it + 1];
            if (c1 >= 1) {
                const unsigned short* gp = G + (size_t)sx * ROW + gcc * CW;
#pragma unroll
                for (int j = 0; j < CP8; ++j) gA[j] = *(const us8v*)(gp + j * 8);
            }
            if (c1 >= 2) {
                const unsigned short* gp = G + (size_t)sy * ROW + gcc * CW;
#pragma unroll
                for (int j = 0; j < CP8; ++j) gB[j] = *(const us8v*)(gp + j * 8);
            }
            if (it + 2 < RG) {
                const int so2 = smO[mb + it + 2], c2 = smO[mb + it + 3] - so2;
                if (c2 >= 1) sx = ssrc[so2];
                if (c2 >= 2) sy = ssrc[so2 + 1];
            }
        }

        // ---- A fragments + MFMA ----
#pragma unroll
        for (int rt = 0; rt < 2; ++rt) {
            const unsigned short* ar = &Ab[(m16 + 16 * rt) * LSS];
#pragma unroll
            for (int ks = 0; ks < KT; ++ks) {
                bf8v af = *(const bf8v*)(ar + ks * 32 + q * 8);
                acc[rt][0] = __builtin_amdgcn_mfma_f32_16x16x32_bf16(af, bfr[0][ks], acc[rt][0], 0, 0, 0);
                acc[rt][1] = __builtin_amdgcn_mfma_f32_16x16x32_bf16(af, bfr[1][ks], acc[rt][1], 0, 0, 0);
            }
        }

        // ---- B fragments for it+1 (root weights after last relation of last group) ----
        const unsigned short* Bp = (it + 1 < RG) ? (Bw + (size_t)(r0 + it + 1) * HID * ROW)
                                                 : (isLast ? Br : nullptr);
        if (Bp) {
#pragma unroll
            for (int ct = 0; ct < 2; ++ct) {
                const int n = colb + 16 * ct + m16;
#pragma unroll
                for (int ks = 0; ks < KT; ++ks)
                    bfr[ct][ks] = *(const bf8v*)(Bp + (size_t)n * ROW + ks * 32 + q * 8);
            }
        }
    }

    // ---- root transform (last group only): A straight from global ----
    if (isLast) {
#pragma unroll
        for (int rt = 0; rt < 2; ++rt) {
#pragma unroll
            for (int ks = 0; ks < KT; ++ks) {
                bf8v af = *(const bf8v*)(G + (size_t)(d0 + m16 + 16 * rt) * ROW + ks * 32 + q * 8);
                acc[rt][0] = __builtin_amdgcn_mfma_f32_16x16x32_bf16(af, bfr[0][ks], acc[rt][0], 0, 0, 0);
                acc[rt][1] = __builtin_amdgcn_mfma_f32_16x16x32_bf16(af, bfr[1][ks], acc[rt][1], 0, 0, 0);
            }
        }
    }

    // ---- epilogue: NONTEMPORAL fp32 partial stores (keep L2 for G/B) ----
    float* pb = part + (size_t)blockIdx.y * N_NODES * HID;
#pragma unroll
    for (int ct = 0; ct < 2; ++ct) {
        const int col = colb + 16 * ct + m16;
#pragma unroll
        for (int rt = 0; rt < 2; ++rt) {
#pragma unroll
            for (int g = 0; g < 4; ++g) {
                const int rr = 16 * rt + q * 4 + g;
                __builtin_nontemporal_store(acc[rt][ct][g],
                    &pb[(size_t)(d0 + rr) * HID + col]);
            }
        }
    }
}

// ======== reduces (nontemporal partial loads) ========
__global__ __launch_bounds__(256) void reduce1_k(
    const float* __restrict__ part, const float* __restrict__ b1,
    unsigned short* __restrict__ h1b) {
    int i = blockIdx.x * 256 + threadIdx.x;   // float4 index
    if (i >= N_NODES * HID / 4) return;
    const size_t S = (size_t)N_NODES * HID;
    float4 a, b;
    const float4* p0 = (const float4*)part + i;
    const float4* p1 = (const float4*)(part + S) + i;
    a.x = __builtin_nontemporal_load(&((const float*)p0)[0]);
    a.y = __builtin_nontemporal_load(&((const float*)p0)[1]);
    a.z = __builtin_nontemporal_load(&((const float*)p0)[2]);
    a.w = __builtin_nontemporal_load(&((const float*)p0)[3]);
    b.x = __builtin_nontemporal_load(&((const float*)p1)[0]);
    b.y = __builtin_nontemporal_load(&((const float*)p1)[1]);
    b.z = __builtin_nontemporal_load(&((const float*)p1)[2]);
    b.w = __builtin_nontemporal_load(&((const float*)p1)[3]);
    float4 bb = *(const float4*)(b1 + ((i * 4) & 127));
    us4v v;
    v[0] = f2b(fmaxf(a.x + b.x + bb.x, 0.0f));
    v[1] = f2b(fmaxf(a.y + b.y + bb.y, 0.0f));
    v[2] = f2b(fmaxf(a.z + b.z + bb.z, 0.0f));
    v[3] = f2b(fmaxf(a.w + b.w + bb.w, 0.0f));
    *(us4v*)(h1b + (size_t)i * 4) = v;
}

__global__ __launch_bounds__(256) void reduce2_k(
    const float* __restrict__ part, const float* __restrict__ b2,
    float* __restrict__ out) {
    int i = blockIdx.x * 256 + threadIdx.x;   // float4 index
    if (i >= N_NODES * HID / 4) return;
    const size_t S = (size_t)N_NODES * HID;
    float4 bb = *(const float4*)(b2 + ((i * 4) & 127));
    float r0 = bb.x, r1 = bb.y, r2 = bb.z, r3 = bb.w;
#pragma unroll
    for (int p = 0; p < 4; ++p) {
        const float* pp = part + p * S + (size_t)i * 4;
        r0 += __builtin_nontemporal_load(pp + 0);
        r1 += __builtin_nontemporal_load(pp + 1);
        r2 += __builtin_nontemporal_load(pp + 2);
        r3 += __builtin_nontemporal_load(pp + 3);
    }
    float4 r; r.x = r0; r.y = r1; r.z = r2; r.w = r3;
    ((float4*)out)[i] = r;
}

extern "C" void kernel_launch(void* const* d_in, const int* in_sizes, int n_in,
                              void* d_out, int out_size, void* d_ws, size_t ws_size,
                              hipStream_t stream) {
    const int*   ei    = (const int*)d_in[0];   // [2, E]
    const int*   et    = (const int*)d_in[1];   // [E]
    const float* x     = (const float*)d_in[2]; // [N, 16]
    const float* W1    = (const float*)d_in[3]; // [32, 16, 128]
    const float* root1 = (const float*)d_in[4]; // [16, 128]
    const float* b1    = (const float*)d_in[5]; // [128]
    const float* W2    = (const float*)d_in[6]; // [32, 128, 128]
    const float* root2 = (const float*)d_in[7]; // [128, 128]
    const float* b2    = (const float*)d_in[8]; // [128]
    float* out = (float*)d_out;

    // ---- workspace layout (~60 MB) ----
    char* ws = (char*)d_ws;
    size_t off = 0;
    auto alloc = [&](size_t bytes) { void* p = ws + off; off = (off + bytes + 63) & ~(size_t)63; return p; };
    int*   hist    = (int*)  alloc((size_t)NB * 4);
    int*   binoff  = (int*)  alloc((size_t)(NB + 1) * 4);
    int*   cursors = (int*)  alloc((size_t)NB * 4);
    float* inv     = (float*)alloc((size_t)NB * 4);
    int*   bsum    = (int*)  alloc(625 * 4);
    int*   bbase   = (int*)  alloc(625 * 4);
    int*   ssrc    = (int*)  alloc((size_t)(N_EDGES + 2) * 4);
    unsigned short* xb  = (unsigned short*)alloc((size_t)N_NODES * 32 * 2);
    unsigned short* h1b = (unsigned short*)alloc((size_t)N_NODES * HID * 2);
    unsigned short* w1t = (unsigned short*)alloc((size_t)N_REL * HID * 32 * 2);
    unsigned short* r1t = (unsigned short*)alloc((size_t)HID * 32 * 2);
    unsigned short* w2t = (unsigned short*)alloc((size_t)N_REL * HID * HID * 2);
    unsigned short* r2t = (unsigned short*)alloc((size_t)HID * HID * 2);
    float* part = (float*)alloc((size_t)4 * N_NODES * HID * 4);   // 4 partials, reused both layers

    const int* src = ei;
    const int* dst = ei + N_EDGES;

    hipMemsetAsync(hist, 0, (size_t)NB * 4, stream);
    pre1_k<<<(PRE_TOT + 255) / 256, 256, 0, stream>>>(
        dst, et, x, W1, root1, W2, root2, hist, xb, w1t, r1t, w2t, r2t);
    scan1_k<<<NB / 1024, 256, 0, stream>>>(hist, binoff, bsum, inv);
    scan2_k<<<1, 1024, 0, stream>>>(bsum, bbase);
    scan3_k<<<(NB + 255) / 256, 256, 0, stream>>>(binoff, bbase, cursors);
    scatter_k<<<(N_EDGES + 255) / 256, 256, 0, stream>>>(src, dst, et, cursors, ssrc);

    // ---- layer 1: 2 relation groups (16 rels each; last adds root) ----
    gemm_f<1, 40, 8, 16><<<dim3(625, 2), 256, 0, stream>>>(
        binoff, inv, ssrc, xb, w1t, r1t, part);
    reduce1_k<<<(N_NODES * HID / 4 + 255) / 256, 256, 0, stream>>>(part, b1, h1b);

    // ---- layer 2: 4 relation groups (8 rels each; last adds root) ----
    gemm_f<4, 136, 16, 8><<<dim3(625, 4), 256, 0, stream>>>(
        binoff, inv, ssrc, h1b, w2t, r2t, part);
    reduce2_k<<<(N_NODES * HID / 4 + 255) / 256, 256, 0, stream>>>(part, b2, out);
}

// Round 16
// 287.321 us; speedup vs baseline: 2.0817x; 1.0573x over previous
//
#include <hip/hip_runtime.h>
#include <hip/hip_bf16.h>

#define N_NODES 20000
#define N_REL 32
#define HID 128
#define EMB 16
#define N_EDGES 600000
#define NB (N_NODES * N_REL)   // 640000 bins

typedef __attribute__((ext_vector_type(8))) short  bf8v;   // 8 bf16 (MFMA A/B frag)
typedef __attribute__((ext_vector_type(8))) unsigned short us8v; // 16-byte unit
typedef __attribute__((ext_vector_type(4))) unsigned short us4v; // 8-byte unit
typedef __attribute__((ext_vector_type(4))) float  f4v;    // MFMA C/D frag

__device__ __forceinline__ unsigned short f2b(float f) {
    __hip_bfloat16 h = __float2bfloat16(f);
    return __builtin_bit_cast(unsigned short, h);
}
__device__ __forceinline__ float b2f(unsigned short u) {
    unsigned int x = ((unsigned int)u) << 16;
    return __builtin_bit_cast(float, x);
}

// Barrier with LDS-only drain (global prefetches stay in flight).
__device__ __forceinline__ void lds_barrier() {
    asm volatile("s_waitcnt lgkmcnt(0)\n\ts_barrier" ::: "memory");
}

// ======== pre-pass: histogram + all bf16 conversions/transposes ========
#define R_W2 (N_REL * HID * HID)        // 1048576
#define R_XB (N_NODES * 32)             // 640000
#define R_W1 (N_REL * HID * 32)         // 131072
#define R_R1 (HID * 32)                 // 4096
#define R_R2 (HID * HID)                // 16384
#define R_HIST N_EDGES                  // 600000
#define PRE_TOT (R_W2 + R_XB + R_W1 + R_R1 + R_R2 + R_HIST)

__global__ __launch_bounds__(256) void pre1_k(
    const int* __restrict__ dst, const int* __restrict__ et,
    const float* __restrict__ x, const float* __restrict__ W1,
    const float* __restrict__ root1, const float* __restrict__ W2,
    const float* __restrict__ root2,
    int* __restrict__ hist,
    unsigned short* __restrict__ xb, unsigned short* __restrict__ w1t,
    unsigned short* __restrict__ r1t, unsigned short* __restrict__ w2t,
    unsigned short* __restrict__ r2t) {
    int i = blockIdx.x * 256 + threadIdx.x;
    if (i < R_W2) {
        int r = i >> 14, k = (i >> 7) & 127, n = i & 127;
        w2t[(r << 14) + (n << 7) + k] = f2b(W2[i]);
        return;
    }
    i -= R_W2;
    if (i < R_XB) {
        int n = i >> 5, k = i & 31;
        xb[i] = (k < EMB) ? f2b(x[n * EMB + k]) : (unsigned short)0;
        return;
    }
    i -= R_XB;
    if (i < R_W1) {
        int r = i >> 12, n = (i >> 5) & 127, k = i & 31;
        w1t[i] = (k < EMB) ? f2b(W1[(r << 11) + (k << 7) + n]) : (unsigned short)0;
        return;
    }
    i -= R_W1;
    if (i < R_R1) {
        int n = i >> 5, k = i & 31;
        r1t[i] = (k < EMB) ? f2b(root1[(k << 7) + n]) : (unsigned short)0;
        return;
    }
    i -= R_R1;
    if (i < R_R2) {
        int n = i >> 7, k = i & 127;
        r2t[i] = f2b(root2[(k << 7) + n]);
        return;
    }
    i -= R_R2;
    if (i < R_HIST) atomicAdd(&hist[dst[i] * N_REL + et[i]], 1);
}

// ======== 2-level exclusive scan over NB = 625 x 1024 (+ inv fused) ========
__global__ void scan1_k(const int* __restrict__ hist, int* __restrict__ binoff,
                        int* __restrict__ bsum, float* __restrict__ inv) {
    __shared__ int sh[256];
    const int t = threadIdx.x;
    const int base = blockIdx.x * 1024 + t * 4;
    int4 h4 = *(const int4*)(hist + base);
    float4 iv4;
    iv4.x = h4.x > 0 ? 1.0f / h4.x : 0.0f;
    iv4.y = h4.y > 0 ? 1.0f / h4.y : 0.0f;
    iv4.z = h4.z > 0 ? 1.0f / h4.z : 0.0f;
    iv4.w = h4.w > 0 ? 1.0f / h4.w : 0.0f;
    *(float4*)(inv + base) = iv4;
    int ts = h4.x + h4.y + h4.z + h4.w;
    sh[t] = ts;
    __syncthreads();
    for (int o = 1; o < 256; o <<= 1) {
        int v = (t >= o) ? sh[t - o] : 0;
        __syncthreads();
        sh[t] += v;
        __syncthreads();
    }
    int exc = sh[t] - ts;
    binoff[base + 0] = exc;
    binoff[base + 1] = exc + h4.x;
    binoff[base + 2] = exc + h4.x + h4.y;
    binoff[base + 3] = exc + h4.x + h4.y + h4.z;
    if (t == 255) bsum[blockIdx.x] = sh[255];
}

__global__ void scan2_k(const int* __restrict__ bsum, int* __restrict__ bbase) {
    __shared__ int sh[1024];
    const int t = threadIdx.x;
    int v = (t < 625) ? bsum[t] : 0;
    sh[t] = v;
    __syncthreads();
    for (int o = 1; o < 1024; o <<= 1) {
        int u = (t >= o) ? sh[t - o] : 0;
        __syncthreads();
        sh[t] += u;
        __syncthreads();
    }
    if (t < 625) bbase[t] = sh[t] - v;
}

__global__ void scan3_k(int* __restrict__ binoff, const int* __restrict__ bbase,
                        int* __restrict__ cursors) {
    int i = blockIdx.x * 256 + threadIdx.x;
    if (i < NB) {
        int v = binoff[i] + bbase[i >> 10];
        binoff[i] = v;
        cursors[i] = v;
    }
    if (i == 0) binoff[NB] = N_EDGES;
}

__global__ void scatter_k(const int* __restrict__ src, const int* __restrict__ dst,
                          const int* __restrict__ et, int* __restrict__ cursors,
                          int* __restrict__ ssrc) {
    int e = blockIdx.x * 256 + threadIdx.x;
    if (e < 4) ssrc[N_EDGES + e] = 0;   // pad: safe src for speculative loads
    if (e < N_EDGES) {
        int b = dst[e] * N_REL + et[e];
        int p = atomicAdd(&cursors[b], 1);
        ssrc[p] = src[e];
    }
}

// ======== fused aggregate+transform, relation-split, fp32 partials ========
// R9/R14 structure with a 4-EDGE staged pipeline: edges 0..3 of iteration
// it+1 are issued (conditionally, exec-masked) right after the barrier of
// iteration it, with their srcs loaded one iteration earlier. The serial
// dependent tail now triggers only for bins with cnt>=5 (P ~2e-3), removing
// the per-iteration block-wide wait on the max-degree thread that made both
// layers' duration a constant ~3.8k cyc/block-iteration.
template<int KT, int LSS, int CW, int RG>
__global__ __launch_bounds__(256) void gemm_f(
    const int* __restrict__ binoff, const float* __restrict__ inv,
    const int* __restrict__ ssrc,
    const unsigned short* __restrict__ G,    // bf16 rows [*, KT*32]
    const unsigned short* __restrict__ Bw,   // bf16 W^T [r][128][KT*32]
    const unsigned short* __restrict__ Br,   // bf16 root^T [128][KT*32]
    float* __restrict__ part) {

    constexpr int ROW = KT * 32;
    constexpr int NCH = ROW / CW;
    constexpr int CP8 = CW / 8;
    static_assert(NCH * CW == ROW, "chunk covering must be exact");
    static_assert(32 * NCH <= 256, "one gather item per thread");

    __shared__ __align__(16) unsigned short As[2][32 * LSS];
    __shared__ int   smO[32 * (RG + 1)];
    __shared__ float smI[32 * RG];

    const int t = threadIdx.x;
    const int w = t >> 6, lane = t & 63;
    const int q = lane >> 4, m16 = lane & 15;
    const int d0 = blockIdx.x * 32;
    const int r0 = blockIdx.y * RG;
    const bool isLast = (blockIdx.y == gridDim.y - 1);
    const int colb = w * 32;
    const bool gat = t < 32 * NCH;
    const int grow = t / NCH, gcc = t % NCH;
    const int mb  = grow * (RG + 1);
    const int mbI = grow * RG;

    // ---- meta preload (this group's bins only) ----
    for (int i = t; i < 32 * (RG + 1); i += 256) {
        int row = i / (RG + 1), rr = i % (RG + 1);
        smO[i] = binoff[(d0 + row) * N_REL + r0 + rr];
    }
    for (int i = t; i < 32 * RG; i += 256) {
        int row = i / RG, rr = i % RG;
        smI[i] = inv[(d0 + row) * N_REL + r0 + rr];
    }
    lds_barrier();

    f4v acc[2][2];
#pragma unroll
    for (int rt = 0; rt < 2; ++rt)
#pragma unroll
        for (int ct = 0; ct < 2; ++ct) acc[rt][ct] = f4v{0.f, 0.f, 0.f, 0.f};

    // ---- staged-edge pipeline state: 4 edges for the CURRENT iteration,
    //      4 src ids for the NEXT iteration ----
    us8v gE[4][CP8];
#pragma unroll
    for (int e = 0; e < 4; ++e)
#pragma unroll
        for (int j = 0; j < CP8; ++j) gE[e][j] = us8v{};
    int sx[4] = {0, 0, 0, 0};

    if (gat) {
        const int so = smO[mb], cnt = smO[mb + 1] - so;
        int s0 = ssrc[so], s1 = ssrc[so + 1], s2 = ssrc[so + 2], s3 = ssrc[so + 3]; // pad-safe
        if (cnt >= 1) {
            const unsigned short* gp = G + (size_t)s0 * ROW + gcc * CW;
#pragma unroll
            for (int j = 0; j < CP8; ++j) gE[0][j] = *(const us8v*)(gp + j * 8);
        }
        if (cnt >= 2) {
            const unsigned short* gp = G + (size_t)s1 * ROW + gcc * CW;
#pragma unroll
            for (int j = 0; j < CP8; ++j) gE[1][j] = *(const us8v*)(gp + j * 8);
        }
        if (cnt >= 3) {
            const unsigned short* gp = G + (size_t)s2 * ROW + gcc * CW;
#pragma unroll
            for (int j = 0; j < CP8; ++j) gE[2][j] = *(const us8v*)(gp + j * 8);
        }
        if (cnt >= 4) {
            const unsigned short* gp = G + (size_t)s3 * ROW + gcc * CW;
#pragma unroll
            for (int j = 0; j < CP8; ++j) gE[3][j] = *(const us8v*)(gp + j * 8);
        }
        if (RG > 1) {
            const int so1 = smO[mb + 1];
            sx[0] = ssrc[so1]; sx[1] = ssrc[so1 + 1];
            sx[2] = ssrc[so1 + 2]; sx[3] = ssrc[so1 + 3];
        }
    }

    // B fragments for it=0
    bf8v bfr[2][KT];
#pragma unroll
    for (int ct = 0; ct < 2; ++ct) {
        const int n = colb + 16 * ct + m16;
#pragma unroll
        for (int ks = 0; ks < KT; ++ks)
            bfr[ct][ks] = *(const bf8v*)(Bw + ((size_t)r0 * HID + n) * ROW + ks * 32 + q * 8);
    }

    for (int it = 0; it < RG; ++it) {
        unsigned short* Ab = As[it & 1];
        // ---- gather (consumes staged edges; iv==0 masks empty bins) ----
        if (gat) {
            const int so = smO[mb + it], eo = smO[mb + it + 1];
            const int cnt = eo - so;
            const float m2 = cnt >= 2 ? 1.f : 0.f;
            const float m3 = cnt >= 3 ? 1.f : 0.f;
            const float m4 = cnt >= 4 ? 1.f : 0.f;
            float a[CW];
#pragma unroll
            for (int j = 0; j < CP8; ++j)
#pragma unroll
                for (int k = 0; k < 8; ++k)
                    a[j * 8 + k] = b2f(gE[0][j][k]) + m2 * b2f(gE[1][j][k])
                                 + m3 * b2f(gE[2][j][k]) + m4 * b2f(gE[3][j][k]);
            for (int p = so + 4; p < eo; ++p) {     // rare tail (P ~2e-3)
                const unsigned short* gp = G + (size_t)ssrc[p] * ROW + gcc * CW;
#pragma unroll
                for (int j = 0; j < CP8; ++j) {
                    us8v g = *(const us8v*)(gp + j * 8);
#pragma unroll
                    for (int k = 0; k < 8; ++k) a[j * 8 + k] += b2f(g[k]);
                }
            }
            const float iv = smI[mbI + it];
            unsigned short* wp = &Ab[grow * LSS + gcc * CW];
#pragma unroll
            for (int j = 0; j < CP8; ++j) {
                us8v sv;
#pragma unroll
                for (int k = 0; k < 8; ++k) sv[k] = f2b(a[j * 8 + k] * iv);
                *(us8v*)(wp + j * 8) = sv;
            }
        }
        lds_barrier();   // LDS-only drain: global prefetches stay in flight

        // ---- post-barrier: issue it+1's 4 edges; load srcs for it+2 ----
        if (gat && it + 1 < RG) {
            const int c1 = smO[mb + it + 2] - smO[mb + it + 1];
            if (c1 >= 1) {
                const unsigned short* gp = G + (size_t)sx[0] * ROW + gcc * CW;
#pragma unroll
                for (int j = 0; j < CP8; ++j) gE[0][j] = *(const us8v*)(gp + j * 8);
            }
            if (c1 >= 2) {
                const unsigned short* gp = G + (size_t)sx[1] * ROW + gcc * CW;
#pragma unroll
                for (int j = 0; j < CP8; ++j) gE[1][j] = *(const us8v*)(gp + j * 8);
            }
            if (c1 >= 3) {
                const unsigned short* gp = G + (size_t)sx[2] * ROW + gcc * CW;
#pragma unroll
                for (int j = 0; j < CP8; ++j) gE[2][j] = *(const us8v*)(gp + j * 8);
            }
            if (c1 >= 4) {
                const unsigned short* gp = G + (size_t)sx[3] * ROW + gcc * CW;
#pragma unroll
                for (int j = 0; j < CP8; ++j) gE[3][j] = *(const us8v*)(gp + j * 8);
            }
            if (it + 2 < RG) {
                const int so2 = smO[mb + it + 2];
                sx[0] = ssrc[so2]; sx[1] = ssrc[so2 + 1];
                sx[2] = ssrc[so2 + 2]; sx[3] = ssrc[so2 + 3];
            }
        }

        // ---- A fragments + MFMA ----
#pragma unroll
        for (int rt = 0; rt < 2; ++rt) {
            const unsigned short* ar = &Ab[(m16 + 16 * rt) * LSS];
#pragma unroll
            for (int ks = 0; ks < KT; ++ks) {
                bf8v af = *(const bf8v*)(ar + ks * 32 + q * 8);
                acc[rt][0] = __builtin_amdgcn_mfma_f32_16x16x32_bf16(af, bfr[0][ks], acc[rt][0], 0, 0, 0);
                acc[rt][1] = __builtin_amdgcn_mfma_f32_16x16x32_bf16(af, bfr[1][ks], acc[rt][1], 0, 0, 0);
            }
        }

        // ---- B fragments for it+1 (root weights after last relation of last group) ----
        const unsigned short* Bp = (it + 1 < RG) ? (Bw + (size_t)(r0 + it + 1) * HID * ROW)
                                                 : (isLast ? Br : nullptr);
        if (Bp) {
#pragma unroll
            for (int ct = 0; ct < 2; ++ct) {
                const int n = colb + 16 * ct + m16;
#pragma unroll
                for (int ks = 0; ks < KT; ++ks)
                    bfr[ct][ks] = *(const bf8v*)(Bp + (size_t)n * ROW + ks * 32 + q * 8);
            }
        }
    }

    // ---- root transform (last group only): A straight from global ----
    if (isLast) {
#pragma unroll
        for (int rt = 0; rt < 2; ++rt) {
#pragma unroll
            for (int ks = 0; ks < KT; ++ks) {
                bf8v af = *(const bf8v*)(G + (size_t)(d0 + m16 + 16 * rt) * ROW + ks * 32 + q * 8);
                acc[rt][0] = __builtin_amdgcn_mfma_f32_16x16x32_bf16(af, bfr[0][ks], acc[rt][0], 0, 0, 0);
                acc[rt][1] = __builtin_amdgcn_mfma_f32_16x16x32_bf16(af, bfr[1][ks], acc[rt][1], 0, 0, 0);
            }
        }
    }

    // ---- epilogue: NONTEMPORAL fp32 partial stores (keep L2 for G/B) ----
    float* pb = part + (size_t)blockIdx.y * N_NODES * HID;
#pragma unroll
    for (int ct = 0; ct < 2; ++ct) {
        const int col = colb + 16 * ct + m16;
#pragma unroll
        for (int rt = 0; rt < 2; ++rt) {
#pragma unroll
            for (int g = 0; g < 4; ++g) {
                const int rr = 16 * rt + q * 4 + g;
                __builtin_nontemporal_store(acc[rt][ct][g],
                    &pb[(size_t)(d0 + rr) * HID + col]);
            }
        }
    }
}

// ======== reduces (nontemporal partial loads) ========
__global__ __launch_bounds__(256) void reduce1_k(
    const float* __restrict__ part, const float* __restrict__ b1,
    unsigned short* __restrict__ h1b) {
    int i = blockIdx.x * 256 + threadIdx.x;   // float4 index
    if (i >= N_NODES * HID / 4) return;
    const size_t S = (size_t)N_NODES * HID;
    float4 bb = *(const float4*)(b1 + ((i * 4) & 127));
    float r0 = bb.x, r1 = bb.y, r2 = bb.z, r3 = bb.w;
#pragma unroll
    for (int p = 0; p < 2; ++p) {
        const float* pp = part + p * S + (size_t)i * 4;
        r0 += __builtin_nontemporal_load(pp + 0);
        r1 += __builtin_nontemporal_load(pp + 1);
        r2 += __builtin_nontemporal_load(pp + 2);
        r3 += __builtin_nontemporal_load(pp + 3);
    }
    us4v v;
    v[0] = f2b(fmaxf(r0, 0.0f));
    v[1] = f2b(fmaxf(r1, 0.0f));
    v[2] = f2b(fmaxf(r2, 0.0f));
    v[3] = f2b(fmaxf(r3, 0.0f));
    *(us4v*)(h1b + (size_t)i * 4) = v;
}

__global__ __launch_bounds__(256) void reduce2_k(
    const float* __restrict__ part, const float* __restrict__ b2,
    float* __restrict__ out) {
    int i = blockIdx.x * 256 + threadIdx.x;   // float4 index
    if (i >= N_NODES * HID / 4) return;
    const size_t S = (size_t)N_NODES * HID;
    float4 bb = *(const float4*)(b2 + ((i * 4) & 127));
    float r0 = bb.x, r1 = bb.y, r2 = bb.z, r3 = bb.w;
#pragma unroll
    for (int p = 0; p < 4; ++p) {
        const float* pp = part + p * S + (size_t)i * 4;
        r0 += __builtin_nontemporal_load(pp + 0);
        r1 += __builtin_nontemporal_load(pp + 1);
        r2 += __builtin_nontemporal_load(pp + 2);
        r3 += __builtin_nontemporal_load(pp + 3);
    }
    float4 r; r.x = r0; r.y = r1; r.z = r2; r.w = r3;
    ((float4*)out)[i] = r;
}

extern "C" void kernel_launch(void* const* d_in, const int* in_sizes, int n_in,
                              void* d_out, int out_size, void* d_ws, size_t ws_size,
                              hipStream_t stream) {
    const int*   ei    = (const int*)d_in[0];   // [2, E]
    const int*   et    = (const int*)d_in[1];   // [E]
    const float* x     = (const float*)d_in[2]; // [N, 16]
    const float* W1    = (const float*)d_in[3]; // [32, 16, 128]
    const float* root1 = (const float*)d_in[4]; // [16, 128]
    const float* b1    = (const float*)d_in[5]; // [128]
    const float* W2    = (const float*)d_in[6]; // [32, 128, 128]
    const float* root2 = (const float*)d_in[7]; // [128, 128]
    const float* b2    = (const float*)d_in[8]; // [128]
    float* out = (float*)d_out;

    // ---- workspace layout (~60 MB) ----
    char* ws = (char*)d_ws;
    size_t off = 0;
    auto alloc = [&](size_t bytes) { void* p = ws + off; off = (off + bytes + 63) & ~(size_t)63; return p; };
    int*   hist    = (int*)  alloc((size_t)NB * 4);
    int*   binoff  = (int*)  alloc((size_t)(NB + 1) * 4);
    int*   cursors = (int*)  alloc((size_t)NB * 4);
    float* inv     = (float*)alloc((size_t)NB * 4);
    int*   bsum    = (int*)  alloc(625 * 4);
    int*   bbase   = (int*)  alloc(625 * 4);
    int*   ssrc    = (int*)  alloc((size_t)(N_EDGES + 4) * 4);
    unsigned short* xb  = (unsigned short*)alloc((size_t)N_NODES * 32 * 2);
    unsigned short* h1b = (unsigned short*)alloc((size_t)N_NODES * HID * 2);
    unsigned short* w1t = (unsigned short*)alloc((size_t)N_REL * HID * 32 * 2);
    unsigned short* r1t = (unsigned short*)alloc((size_t)HID * 32 * 2);
    unsigned short* w2t = (unsigned short*)alloc((size_t)N_REL * HID * HID * 2);
    unsigned short* r2t = (unsigned short*)alloc((size_t)HID * HID * 2);
    float* part = (float*)alloc((size_t)4 * N_NODES * HID * 4);   // 4 partials, reused both layers

    const int* src = ei;
    const int* dst = ei + N_EDGES;

    hipMemsetAsync(hist, 0, (size_t)NB * 4, stream);
    pre1_k<<<(PRE_TOT + 255) / 256, 256, 0, stream>>>(
        dst, et, x, W1, root1, W2, root2, hist, xb, w1t, r1t, w2t, r2t);
    scan1_k<<<NB / 1024, 256, 0, stream>>>(hist, binoff, bsum, inv);
    scan2_k<<<1, 1024, 0, stream>>>(bsum, bbase);
    scan3_k<<<(NB + 255) / 256, 256, 0, stream>>>(binoff, bbase, cursors);
    scatter_k<<<(N_EDGES + 255) / 256, 256, 0, stream>>>(src, dst, et, cursors, ssrc);

    // ---- layer 1: 2 relation groups (16 rels each; last adds root) ----
    gemm_f<1, 40, 8, 16><<<dim3(625, 2), 256, 0, stream>>>(
        binoff, inv, ssrc, xb, w1t, r1t, part);
    reduce1_k<<<(N_NODES * HID / 4 + 255) / 256, 256, 0, stream>>>(part, b1, h1b);

    // ---- layer 2: 4 relation groups (8 rels each; last adds root) ----
    gemm_f<4, 136, 16, 8><<<dim3(625, 4), 256, 0, stream>>>(
        binoff, inv, ssrc, h1b, w2t, r2t, part);
    reduce2_k<<<(N_NODES * HID / 4 + 255) / 256, 256, 0, stream>>>(part, b2, out);
}

// Round 17
// 283.440 us; speedup vs baseline: 2.1102x; 1.0137x over previous
//
#include <hip/hip_runtime.h>
#include <hip/hip_bf16.h>

#define N_NODES 20000
#define N_REL 32
#define HID 128
#define EMB 16
#define N_EDGES 600000
#define NB (N_NODES * N_REL)   // 640000 bins

typedef __attribute__((ext_vector_type(8))) short  bf8v;   // 8 bf16 (MFMA A/B frag)
typedef __attribute__((ext_vector_type(8))) unsigned short us8v; // 16-byte unit
typedef __attribute__((ext_vector_type(4))) unsigned short us4v; // 8-byte unit
typedef __attribute__((ext_vector_type(4))) float  f4v;    // MFMA C/D frag

__device__ __forceinline__ unsigned short f2b(float f) {
    __hip_bfloat16 h = __float2bfloat16(f);
    return __builtin_bit_cast(unsigned short, h);
}
__device__ __forceinline__ float b2f(unsigned short u) {
    unsigned int x = ((unsigned int)u) << 16;
    return __builtin_bit_cast(float, x);
}

// Barrier with LDS-only drain (global prefetches stay in flight).
__device__ __forceinline__ void lds_barrier() {
    asm volatile("s_waitcnt lgkmcnt(0)\n\ts_barrier" ::: "memory");
}

// ======== pre-pass: histogram + all bf16 conversions/transposes ========
#define R_W2 (N_REL * HID * HID)        // 1048576
#define R_XB (N_NODES * 32)             // 640000
#define R_W1 (N_REL * HID * 32)         // 131072
#define R_R1 (HID * 32)                 // 4096
#define R_R2 (HID * HID)                // 16384
#define R_HIST N_EDGES                  // 600000
#define PRE_TOT (R_W2 + R_XB + R_W1 + R_R1 + R_R2 + R_HIST)

__global__ __launch_bounds__(256) void pre1_k(
    const int* __restrict__ dst, const int* __restrict__ et,
    const float* __restrict__ x, const float* __restrict__ W1,
    const float* __restrict__ root1, const float* __restrict__ W2,
    const float* __restrict__ root2,
    int* __restrict__ hist,
    unsigned short* __restrict__ xb, unsigned short* __restrict__ w1t,
    unsigned short* __restrict__ r1t, unsigned short* __restrict__ w2t,
    unsigned short* __restrict__ r2t) {
    int i = blockIdx.x * 256 + threadIdx.x;
    if (i < R_W2) {
        int r = i >> 14, k = (i >> 7) & 127, n = i & 127;
        w2t[(r << 14) + (n << 7) + k] = f2b(W2[i]);
        return;
    }
    i -= R_W2;
    if (i < R_XB) {
        int n = i >> 5, k = i & 31;
        xb[i] = (k < EMB) ? f2b(x[n * EMB + k]) : (unsigned short)0;
        return;
    }
    i -= R_XB;
    if (i < R_W1) {
        int r = i >> 12, n = (i >> 5) & 127, k = i & 31;
        w1t[i] = (k < EMB) ? f2b(W1[(r << 11) + (k << 7) + n]) : (unsigned short)0;
        return;
    }
    i -= R_W1;
    if (i < R_R1) {
        int n = i >> 5, k = i & 31;
        r1t[i] = (k < EMB) ? f2b(root1[(k << 7) + n]) : (unsigned short)0;
        return;
    }
    i -= R_R1;
    if (i < R_R2) {
        int n = i >> 7, k = i & 127;
        r2t[i] = f2b(root2[(k << 7) + n]);
        return;
    }
    i -= R_R2;
    if (i < R_HIST) atomicAdd(&hist[dst[i] * N_REL + et[i]], 1);
}

// ======== 2-level exclusive scan over NB = 625 x 1024 (+ inv fused) ========
__global__ void scan1_k(const int* __restrict__ hist, int* __restrict__ binoff,
                        int* __restrict__ bsum, float* __restrict__ inv) {
    __shared__ int sh[256];
    const int t = threadIdx.x;
    const int base = blockIdx.x * 1024 + t * 4;
    int4 h4 = *(const int4*)(hist + base);
    float4 iv4;
    iv4.x = h4.x > 0 ? 1.0f / h4.x : 0.0f;
    iv4.y = h4.y > 0 ? 1.0f / h4.y : 0.0f;
    iv4.z = h4.z > 0 ? 1.0f / h4.z : 0.0f;
    iv4.w = h4.w > 0 ? 1.0f / h4.w : 0.0f;
    *(float4*)(inv + base) = iv4;
    int ts = h4.x + h4.y + h4.z + h4.w;
    sh[t] = ts;
    __syncthreads();
    for (int o = 1; o < 256; o <<= 1) {
        int v = (t >= o) ? sh[t - o] : 0;
        __syncthreads();
        sh[t] += v;
        __syncthreads();
    }
    int exc = sh[t] - ts;
    binoff[base + 0] = exc;
    binoff[base + 1] = exc + h4.x;
    binoff[base + 2] = exc + h4.x + h4.y;
    binoff[base + 3] = exc + h4.x + h4.y + h4.z;
    if (t == 255) bsum[blockIdx.x] = sh[255];
}

__global__ void scan2_k(const int* __restrict__ bsum, int* __restrict__ bbase) {
    __shared__ int sh[1024];
    const int t = threadIdx.x;
    int v = (t < 625) ? bsum[t] : 0;
    sh[t] = v;
    __syncthreads();
    for (int o = 1; o < 1024; o <<= 1) {
        int u = (t >= o) ? sh[t - o] : 0;
        __syncthreads();
        sh[t] += u;
        __syncthreads();
    }
    if (t < 625) bbase[t] = sh[t] - v;
}

__global__ void scan3_k(int* __restrict__ binoff, const int* __restrict__ bbase,
                        int* __restrict__ cursors) {
    int i = blockIdx.x * 256 + threadIdx.x;
    if (i < NB) {
        int v = binoff[i] + bbase[i >> 10];
        binoff[i] = v;
        cursors[i] = v;
    }
    if (i == 0) binoff[NB] = N_EDGES;
}

__global__ void scatter_k(const int* __restrict__ src, const int* __restrict__ dst,
                          const int* __restrict__ et, int* __restrict__ cursors,
                          int* __restrict__ ssrc) {
    int e = blockIdx.x * 256 + threadIdx.x;
    if (e < 4) ssrc[N_EDGES + e] = 0;   // pad: safe src for speculative loads
    if (e < N_EDGES) {
        int b = dst[e] * N_REL + et[e];
        int p = atomicAdd(&cursors[b], 1);
        ssrc[p] = src[e];
    }
}

// ======== fused aggregate+transform, relation-split, fp32 partials ========
// R15 structure (4-edge staged pipeline) with ONE code-motion change: the
// staged G(it+1) edge loads + srcs(it+2) loads are issued BEFORE the
// lds_barrier (right after the A-tile ds_writes). Because lds_barrier does
// not drain vmcnt, those loads stay in flight across the barrier, so their
// landing window = barrier-wait + MFMA section (a full iteration) instead
// of just the MFMA section — enough to cover the ~12% HBM-miss gathers
// (~900 cyc) that previously serialized every iteration at the barrier.
template<int KT, int LSS, int CW, int RG>
__global__ __launch_bounds__(256) void gemm_f(
    const int* __restrict__ binoff, const float* __restrict__ inv,
    const int* __restrict__ ssrc,
    const unsigned short* __restrict__ G,    // bf16 rows [*, KT*32]
    const unsigned short* __restrict__ Bw,   // bf16 W^T [r][128][KT*32]
    const unsigned short* __restrict__ Br,   // bf16 root^T [128][KT*32]
    float* __restrict__ part) {

    constexpr int ROW = KT * 32;
    constexpr int NCH = ROW / CW;
    constexpr int CP8 = CW / 8;
    static_assert(NCH * CW == ROW, "chunk covering must be exact");
    static_assert(32 * NCH <= 256, "one gather item per thread");

    __shared__ __align__(16) unsigned short As[2][32 * LSS];
    __shared__ int   smO[32 * (RG + 1)];
    __shared__ float smI[32 * RG];

    const int t = threadIdx.x;
    const int w = t >> 6, lane = t & 63;
    const int q = lane >> 4, m16 = lane & 15;
    const int d0 = blockIdx.x * 32;
    const int r0 = blockIdx.y * RG;
    const bool isLast = (blockIdx.y == gridDim.y - 1);
    const int colb = w * 32;
    const bool gat = t < 32 * NCH;
    const int grow = t / NCH, gcc = t % NCH;
    const int mb  = grow * (RG + 1);
    const int mbI = grow * RG;

    // ---- meta preload (this group's bins only) ----
    for (int i = t; i < 32 * (RG + 1); i += 256) {
        int row = i / (RG + 1), rr = i % (RG + 1);
        smO[i] = binoff[(d0 + row) * N_REL + r0 + rr];
    }
    for (int i = t; i < 32 * RG; i += 256) {
        int row = i / RG, rr = i % RG;
        smI[i] = inv[(d0 + row) * N_REL + r0 + rr];
    }
    lds_barrier();

    f4v acc[2][2];
#pragma unroll
    for (int rt = 0; rt < 2; ++rt)
#pragma unroll
        for (int ct = 0; ct < 2; ++ct) acc[rt][ct] = f4v{0.f, 0.f, 0.f, 0.f};

    // ---- staged-edge pipeline state ----
    us8v gE[4][CP8];
#pragma unroll
    for (int e = 0; e < 4; ++e)
#pragma unroll
        for (int j = 0; j < CP8; ++j) gE[e][j] = us8v{};
    int sx[4] = {0, 0, 0, 0};

    if (gat) {
        const int so = smO[mb], cnt = smO[mb + 1] - so;
        int s0 = ssrc[so], s1 = ssrc[so + 1], s2 = ssrc[so + 2], s3 = ssrc[so + 3]; // pad-safe
        if (cnt >= 1) {
            const unsigned short* gp = G + (size_t)s0 * ROW + gcc * CW;
#pragma unroll
            for (int j = 0; j < CP8; ++j) gE[0][j] = *(const us8v*)(gp + j * 8);
        }
        if (cnt >= 2) {
            const unsigned short* gp = G + (size_t)s1 * ROW + gcc * CW;
#pragma unroll
            for (int j = 0; j < CP8; ++j) gE[1][j] = *(const us8v*)(gp + j * 8);
        }
        if (cnt >= 3) {
            const unsigned short* gp = G + (size_t)s2 * ROW + gcc * CW;
#pragma unroll
            for (int j = 0; j < CP8; ++j) gE[2][j] = *(const us8v*)(gp + j * 8);
        }
        if (cnt >= 4) {
            const unsigned short* gp = G + (size_t)s3 * ROW + gcc * CW;
#pragma unroll
            for (int j = 0; j < CP8; ++j) gE[3][j] = *(const us8v*)(gp + j * 8);
        }
        if (RG > 1) {
            const int so1 = smO[mb + 1];
            sx[0] = ssrc[so1]; sx[1] = ssrc[so1 + 1];
            sx[2] = ssrc[so1 + 2]; sx[3] = ssrc[so1 + 3];
        }
    }

    // B fragments for it=0
    bf8v bfr[2][KT];
#pragma unroll
    for (int ct = 0; ct < 2; ++ct) {
        const int n = colb + 16 * ct + m16;
#pragma unroll
        for (int ks = 0; ks < KT; ++ks)
            bfr[ct][ks] = *(const bf8v*)(Bw + ((size_t)r0 * HID + n) * ROW + ks * 32 + q * 8);
    }

    for (int it = 0; it < RG; ++it) {
        unsigned short* Ab = As[it & 1];
        // ---- gather (consumes staged edges) + PRE-BARRIER prefetch issue ----
        if (gat) {
            const int so = smO[mb + it], eo = smO[mb + it + 1];
            const int cnt = eo - so;
            const float m2 = cnt >= 2 ? 1.f : 0.f;
            const float m3 = cnt >= 3 ? 1.f : 0.f;
            const float m4 = cnt >= 4 ? 1.f : 0.f;
            float a[CW];
#pragma unroll
            for (int j = 0; j < CP8; ++j)
#pragma unroll
                for (int k = 0; k < 8; ++k)
                    a[j * 8 + k] = b2f(gE[0][j][k]) + m2 * b2f(gE[1][j][k])
                                 + m3 * b2f(gE[2][j][k]) + m4 * b2f(gE[3][j][k]);
            for (int p = so + 4; p < eo; ++p) {     // rare tail (P ~2e-3)
                const unsigned short* gp = G + (size_t)ssrc[p] * ROW + gcc * CW;
#pragma unroll
                for (int j = 0; j < CP8; ++j) {
                    us8v g = *(const us8v*)(gp + j * 8);
#pragma unroll
                    for (int k = 0; k < 8; ++k) a[j * 8 + k] += b2f(g[k]);
                }
            }
            const float iv = smI[mbI + it];
            unsigned short* wp = &Ab[grow * LSS + gcc * CW];
#pragma unroll
            for (int j = 0; j < CP8; ++j) {
                us8v sv;
#pragma unroll
                for (int k = 0; k < 8; ++k) sv[k] = f2b(a[j * 8 + k] * iv);
                *(us8v*)(wp + j * 8) = sv;
            }

            // ---- PRE-BARRIER: issue it+1's 4 staged edges + srcs for it+2.
            //      These ride across lds_barrier (no vmcnt drain) and land
            //      during barrier-wait + MFMA — a full-iteration window. ----
            if (it + 1 < RG) {
                const int c1 = smO[mb + it + 2] - smO[mb + it + 1];
                if (c1 >= 1) {
                    const unsigned short* gp = G + (size_t)sx[0] * ROW + gcc * CW;
#pragma unroll
                    for (int j = 0; j < CP8; ++j) gE[0][j] = *(const us8v*)(gp + j * 8);
                }
                if (c1 >= 2) {
                    const unsigned short* gp = G + (size_t)sx[1] * ROW + gcc * CW;
#pragma unroll
                    for (int j = 0; j < CP8; ++j) gE[1][j] = *(const us8v*)(gp + j * 8);
                }
                if (c1 >= 3) {
                    const unsigned short* gp = G + (size_t)sx[2] * ROW + gcc * CW;
#pragma unroll
                    for (int j = 0; j < CP8; ++j) gE[2][j] = *(const us8v*)(gp + j * 8);
                }
                if (c1 >= 4) {
                    const unsigned short* gp = G + (size_t)sx[3] * ROW + gcc * CW;
#pragma unroll
                    for (int j = 0; j < CP8; ++j) gE[3][j] = *(const us8v*)(gp + j * 8);
                }
                if (it + 2 < RG) {
                    const int so2 = smO[mb + it + 2];
                    sx[0] = ssrc[so2]; sx[1] = ssrc[so2 + 1];
                    sx[2] = ssrc[so2 + 2]; sx[3] = ssrc[so2 + 3];
                }
            }
        }
        lds_barrier();   // LDS-only drain: all global prefetches stay in flight

        // ---- A fragments + MFMA ----
#pragma unroll
        for (int rt = 0; rt < 2; ++rt) {
            const unsigned short* ar = &Ab[(m16 + 16 * rt) * LSS];
#pragma unroll
            for (int ks = 0; ks < KT; ++ks) {
                bf8v af = *(const bf8v*)(ar + ks * 32 + q * 8);
                acc[rt][0] = __builtin_amdgcn_mfma_f32_16x16x32_bf16(af, bfr[0][ks], acc[rt][0], 0, 0, 0);
                acc[rt][1] = __builtin_amdgcn_mfma_f32_16x16x32_bf16(af, bfr[1][ks], acc[rt][1], 0, 0, 0);
            }
        }

        // ---- B fragments for it+1 (root weights after last relation of last group) ----
        const unsigned short* Bp = (it + 1 < RG) ? (Bw + (size_t)(r0 + it + 1) * HID * ROW)
                                                 : (isLast ? Br : nullptr);
        if (Bp) {
#pragma unroll
            for (int ct = 0; ct < 2; ++ct) {
                const int n = colb + 16 * ct + m16;
#pragma unroll
                for (int ks = 0; ks < KT; ++ks)
                    bfr[ct][ks] = *(const bf8v*)(Bp + (size_t)n * ROW + ks * 32 + q * 8);
            }
        }
    }

    // ---- root transform (last group only): A straight from global ----
    if (isLast) {
#pragma unroll
        for (int rt = 0; rt < 2; ++rt) {
#pragma unroll
            for (int ks = 0; ks < KT; ++ks) {
                bf8v af = *(const bf8v*)(G + (size_t)(d0 + m16 + 16 * rt) * ROW + ks * 32 + q * 8);
                acc[rt][0] = __builtin_amdgcn_mfma_f32_16x16x32_bf16(af, bfr[0][ks], acc[rt][0], 0, 0, 0);
                acc[rt][1] = __builtin_amdgcn_mfma_f32_16x16x32_bf16(af, bfr[1][ks], acc[rt][1], 0, 0, 0);
            }
        }
    }

    // ---- epilogue: NONTEMPORAL fp32 partial stores (keep L2 for G/B) ----
    float* pb = part + (size_t)blockIdx.y * N_NODES * HID;
#pragma unroll
    for (int ct = 0; ct < 2; ++ct) {
        const int col = colb + 16 * ct + m16;
#pragma unroll
        for (int rt = 0; rt < 2; ++rt) {
#pragma unroll
            for (int g = 0; g < 4; ++g) {
                const int rr = 16 * rt + q * 4 + g;
                __builtin_nontemporal_store(acc[rt][ct][g],
                    &pb[(size_t)(d0 + rr) * HID + col]);
            }
        }
    }
}

// ======== reduces (nontemporal partial loads) ========
__global__ __launch_bounds__(256) void reduce1_k(
    const float* __restrict__ part, const float* __restrict__ b1,
    unsigned short* __restrict__ h1b) {
    int i = blockIdx.x * 256 + threadIdx.x;   // float4 index
    if (i >= N_NODES * HID / 4) return;
    const size_t S = (size_t)N_NODES * HID;
    float4 bb = *(const float4*)(b1 + ((i * 4) & 127));
    float r0 = bb.x, r1 = bb.y, r2 = bb.z, r3 = bb.w;
#pragma unroll
    for (int p = 0; p < 2; ++p) {
        const float* pp = part + p * S + (size_t)i * 4;
        r0 += __builtin_nontemporal_load(pp + 0);
        r1 += __builtin_nontemporal_load(pp + 1);
        r2 += __builtin_nontemporal_load(pp + 2);
        r3 += __builtin_nontemporal_load(pp + 3);
    }
    us4v v;
    v[0] = f2b(fmaxf(r0, 0.0f));
    v[1] = f2b(fmaxf(r1, 0.0f));
    v[2] = f2b(fmaxf(r2, 0.0f));
    v[3] = f2b(fmaxf(r3, 0.0f));
    *(us4v*)(h1b + (size_t)i * 4) = v;
}

__global__ __launch_bounds__(256) void reduce2_k(
    const float* __restrict__ part, const float* __restrict__ b2,
    float* __restrict__ out) {
    int i = blockIdx.x * 256 + threadIdx.x;   // float4 index
    if (i >= N_NODES * HID / 4) return;
    const size_t S = (size_t)N_NODES * HID;
    float4 bb = *(const float4*)(b2 + ((i * 4) & 127));
    float r0 = bb.x, r1 = bb.y, r2 = bb.z, r3 = bb.w;
#pragma unroll
    for (int p = 0; p < 4; ++p) {
        const float* pp = part + p * S + (size_t)i * 4;
        r0 += __builtin_nontemporal_load(pp + 0);
        r1 += __builtin_nontemporal_load(pp + 1);
        r2 += __builtin_nontemporal_load(pp + 2);
        r3 += __builtin_nontemporal_load(pp + 3);
    }
    float4 r; r.x = r0; r.y = r1; r.z = r2; r.w = r3;
    ((float4*)out)[i] = r;
}

extern "C" void kernel_launch(void* const* d_in, const int* in_sizes, int n_in,
                              void* d_out, int out_size, void* d_ws, size_t ws_size,
                              hipStream_t stream) {
    const int*   ei    = (const int*)d_in[0];   // [2, E]
    const int*   et    = (const int*)d_in[1];   // [E]
    const float* x     = (const float*)d_in[2]; // [N, 16]
    const float* W1    = (const float*)d_in[3]; // [32, 16, 128]
    const float* root1 = (const float*)d_in[4]; // [16, 128]
    const float* b1    = (const float*)d_in[5]; // [128]
    const float* W2    = (const float*)d_in[6]; // [32, 128, 128]
    const float* root2 = (const float*)d_in[7]; // [128, 128]
    const float* b2    = (const float*)d_in[8]; // [128]
    float* out = (float*)d_out;

    // ---- workspace layout (~60 MB) ----
    char* ws = (char*)d_ws;
    size_t off = 0;
    auto alloc = [&](size_t bytes) { void* p = ws + off; off = (off + bytes + 63) & ~(size_t)63; return p; };
    int*   hist    = (int*)  alloc((size_t)NB * 4);
    int*   binoff  = (int*)  alloc((size_t)(NB + 1) * 4);
    int*   cursors = (int*)  alloc((size_t)NB * 4);
    float* inv     = (float*)alloc((size_t)NB * 4);
    int*   bsum    = (int*)  alloc(625 * 4);
    int*   bbase   = (int*)  alloc(625 * 4);
    int*   ssrc    = (int*)  alloc((size_t)(N_EDGES + 4) * 4);
    unsigned short* xb  = (unsigned short*)alloc((size_t)N_NODES * 32 * 2);
    unsigned short* h1b = (unsigned short*)alloc((size_t)N_NODES * HID * 2);
    unsigned short* w1t = (unsigned short*)alloc((size_t)N_REL * HID * 32 * 2);
    unsigned short* r1t = (unsigned short*)alloc((size_t)HID * 32 * 2);
    unsigned short* w2t = (unsigned short*)alloc((size_t)N_REL * HID * HID * 2);
    unsigned short* r2t = (unsigned short*)alloc((size_t)HID * HID * 2);
    float* part = (float*)alloc((size_t)4 * N_NODES * HID * 4);   // 4 partials, reused both layers

    const int* src = ei;
    const int* dst = ei + N_EDGES;

    hipMemsetAsync(hist, 0, (size_t)NB * 4, stream);
    pre1_k<<<(PRE_TOT + 255) / 256, 256, 0, stream>>>(
        dst, et, x, W1, root1, W2, root2, hist, xb, w1t, r1t, w2t, r2t);
    scan1_k<<<NB / 1024, 256, 0, stream>>>(hist, binoff, bsum, inv);
    scan2_k<<<1, 1024, 0, stream>>>(bsum, bbase);
    scan3_k<<<(NB + 255) / 256, 256, 0, stream>>>(binoff, bbase, cursors);
    scatter_k<<<(N_EDGES + 255) / 256, 256, 0, stream>>>(src, dst, et, cursors, ssrc);

    // ---- layer 1: 2 relation groups (16 rels each; last adds root) ----
    gemm_f<1, 40, 8, 16><<<dim3(625, 2), 256, 0, stream>>>(
        binoff, inv, ssrc, xb, w1t, r1t, part);
    reduce1_k<<<(N_NODES * HID / 4 + 255) / 256, 256, 0, stream>>>(part, b1, h1b);

    // ---- layer 2: 4 relation groups (8 rels each; last adds root) ----
    gemm_f<4, 136, 16, 8><<<dim3(625, 4), 256, 0, stream>>>(
        binoff, inv, ssrc, h1b, w2t, r2t, part);
    reduce2_k<<<(N_NODES * HID / 4 + 255) / 256, 256, 0, stream>>>(part, b2, out);
}

// Round 18
// 246.514 us; speedup vs baseline: 2.4263x; 1.1498x over previous
//
#include <hip/hip_runtime.h>
#include <hip/hip_bf16.h>

#define N_NODES 20000
#define N_REL 32
#define HID 128
#define EMB 16
#define N_EDGES 600000
#define NB (N_NODES * N_REL)   // 640000 bins

typedef __attribute__((ext_vector_type(8))) short  bf8v;   // 8 bf16 (MFMA A/B frag)
typedef __attribute__((ext_vector_type(8))) unsigned short us8v; // 16-byte unit
typedef __attribute__((ext_vector_type(4))) unsigned short us4v; // 8-byte unit
typedef __attribute__((ext_vector_type(4))) float  f4v;    // MFMA C/D frag

__device__ __forceinline__ unsigned short f2b(float f) {
    __hip_bfloat16 h = __float2bfloat16(f);
    return __builtin_bit_cast(unsigned short, h);
}
__device__ __forceinline__ float b2f(unsigned short u) {
    unsigned int x = ((unsigned int)u) << 16;
    return __builtin_bit_cast(float, x);
}

// Barrier with LDS-only drain (global prefetches stay in flight).
__device__ __forceinline__ void lds_barrier() {
    asm volatile("s_waitcnt lgkmcnt(0)\n\ts_barrier" ::: "memory");
}

// ======== pre-pass: histogram + fragment-major bf16 weight layouts ========
// Weight layout (fragment-major): B[r][ct8][ks][m16][q][j8]
//   ct8 = coltile (n>>4), m16 = n&15, ks = k>>5, q = (k>>3)&3, j = k&7.
// A wave's fragment load (lanes (q,m16)) covers one CONTIGUOUS 1 KB block.
#define R_W2 (N_REL * HID * HID)        // 1048576
#define R_XB (N_NODES * 32)             // 640000
#define R_W1 (N_REL * HID * 32)         // 131072
#define R_R1 (HID * 32)                 // 4096
#define R_R2 (HID * HID)                // 16384
#define R_HIST N_EDGES                  // 600000
#define PRE_TOT (R_W2 + R_XB + R_W1 + R_R1 + R_R2 + R_HIST)

__global__ __launch_bounds__(256) void pre1_k(
    const int* __restrict__ dst, const int* __restrict__ et,
    const float* __restrict__ x, const float* __restrict__ W1,
    const float* __restrict__ root1, const float* __restrict__ W2,
    const float* __restrict__ root2,
    int* __restrict__ hist,
    unsigned short* __restrict__ xb, unsigned short* __restrict__ w1t,
    unsigned short* __restrict__ r1t, unsigned short* __restrict__ w2t,
    unsigned short* __restrict__ r2t) {
    int i = blockIdx.x * 256 + threadIdx.x;
    if (i < R_W2) {
        // coalesced read of W2 [r][k][n]; scattered fragment-major write (KT=4)
        int r = i >> 14, k = (i >> 7) & 127, n = i & 127;
        int ct8 = n >> 4, m16 = n & 15, ks = k >> 5, q = (k >> 3) & 3, j = k & 7;
        w2t[(size_t)r * 16384 + (ct8 * 4 + ks) * 512 + m16 * 32 + q * 8 + j] = f2b(W2[i]);
        return;
    }
    i -= R_W2;
    if (i < R_XB) {
        int n = i >> 5, k = i & 31;
        xb[i] = (k < EMB) ? f2b(x[n * EMB + k]) : (unsigned short)0;
        return;
    }
    i -= R_XB;
    if (i < R_W1) {
        // dst-linear fragment-major (KT=1): i = r*4096 + ct8*512 + m16*32 + q*8 + j
        int r = i >> 12, rem = i & 4095;
        int ct8 = rem >> 9, m16 = (rem >> 5) & 15, q = (rem >> 3) & 3, j = rem & 7;
        int n = ct8 * 16 + m16, k = q * 8 + j;
        w1t[i] = (k < EMB) ? f2b(W1[(r << 11) + (k << 7) + n]) : (unsigned short)0;
        return;
    }
    i -= R_W1;
    if (i < R_R1) {
        // dst-linear fragment-major (KT=1)
        int ct8 = i >> 9, m16 = (i >> 5) & 15, q = (i >> 3) & 3, j = i & 7;
        int n = ct8 * 16 + m16, k = q * 8 + j;
        r1t[i] = (k < EMB) ? f2b(root1[(k << 7) + n]) : (unsigned short)0;
        return;
    }
    i -= R_R1;
    if (i < R_R2) {
        // dst-linear fragment-major (KT=4)
        int ct8 = i >> 11, ks = (i >> 9) & 3, m16 = (i >> 5) & 15, q = (i >> 3) & 3, j = i & 7;
        int n = ct8 * 16 + m16, k = ks * 32 + q * 8 + j;
        r2t[i] = f2b(root2[(k << 7) + n]);
        return;
    }
    i -= R_R2;
    if (i < R_HIST) atomicAdd(&hist[dst[i] * N_REL + et[i]], 1);
}

// ======== 2-level exclusive scan over NB = 625 x 1024 (+ inv fused) ========
__global__ void scan1_k(const int* __restrict__ hist, int* __restrict__ binoff,
                        int* __restrict__ bsum, float* __restrict__ inv) {
    __shared__ int sh[256];
    const int t = threadIdx.x;
    const int base = blockIdx.x * 1024 + t * 4;
    int4 h4 = *(const int4*)(hist + base);
    float4 iv4;
    iv4.x = h4.x > 0 ? 1.0f / h4.x : 0.0f;
    iv4.y = h4.y > 0 ? 1.0f / h4.y : 0.0f;
    iv4.z = h4.z > 0 ? 1.0f / h4.z : 0.0f;
    iv4.w = h4.w > 0 ? 1.0f / h4.w : 0.0f;
    *(float4*)(inv + base) = iv4;
    int ts = h4.x + h4.y + h4.z + h4.w;
    sh[t] = ts;
    __syncthreads();
    for (int o = 1; o < 256; o <<= 1) {
        int v = (t >= o) ? sh[t - o] : 0;
        __syncthreads();
        sh[t] += v;
        __syncthreads();
    }
    int exc = sh[t] - ts;
    binoff[base + 0] = exc;
    binoff[base + 1] = exc + h4.x;
    binoff[base + 2] = exc + h4.x + h4.y;
    binoff[base + 3] = exc + h4.x + h4.y + h4.z;
    if (t == 255) bsum[blockIdx.x] = sh[255];
}

__global__ void scan2_k(const int* __restrict__ bsum, int* __restrict__ bbase) {
    __shared__ int sh[1024];
    const int t = threadIdx.x;
    int v = (t < 625) ? bsum[t] : 0;
    sh[t] = v;
    __syncthreads();
    for (int o = 1; o < 1024; o <<= 1) {
        int u = (t >= o) ? sh[t - o] : 0;
        __syncthreads();
        sh[t] += u;
        __syncthreads();
    }
    if (t < 625) bbase[t] = sh[t] - v;
}

__global__ void scan3_k(int* __restrict__ binoff, const int* __restrict__ bbase,
                        int* __restrict__ cursors) {
    int i = blockIdx.x * 256 + threadIdx.x;
    if (i < NB) {
        int v = binoff[i] + bbase[i >> 10];
        binoff[i] = v;
        cursors[i] = v;
    }
    if (i == 0) binoff[NB] = N_EDGES;
}

__global__ void scatter_k(const int* __restrict__ src, const int* __restrict__ dst,
                          const int* __restrict__ et, int* __restrict__ cursors,
                          int* __restrict__ ssrc) {
    int e = blockIdx.x * 256 + threadIdx.x;
    if (e < 4) ssrc[N_EDGES + e] = 0;   // pad: safe src for speculative loads
    if (e < N_EDGES) {
        int b = dst[e] * N_REL + et[e];
        int p = atomicAdd(&cursors[b], 1);
        ssrc[p] = src[e];
    }
}

// ======== fused aggregate+transform, relation-split, fp32 partials ========
// R16 structure; B/root weights are FRAGMENT-MAJOR so every bfr load is one
// contiguous 1 KB wave-read (16 sequential cache lines) instead of 16
// scattered lines — attacks the TA/L1 line-processing constant that all
// barriered variants plateaued on (~3.4k cyc/block-iteration).
template<int KT, int LSS, int CW, int RG>
__global__ __launch_bounds__(256) void gemm_f(
    const int* __restrict__ binoff, const float* __restrict__ inv,
    const int* __restrict__ ssrc,
    const unsigned short* __restrict__ G,    // bf16 rows [*, KT*32]
    const unsigned short* __restrict__ Bw,   // bf16 frag-major [r][ct8][ks][512]
    const unsigned short* __restrict__ Br,   // bf16 frag-major [ct8][ks][512]
    float* __restrict__ part) {

    constexpr int ROW = KT * 32;
    constexpr int NCH = ROW / CW;
    constexpr int CP8 = CW / 8;
    static_assert(NCH * CW == ROW, "chunk covering must be exact");
    static_assert(32 * NCH <= 256, "one gather item per thread");

    __shared__ __align__(16) unsigned short As[2][32 * LSS];
    __shared__ int   smO[32 * (RG + 1)];
    __shared__ float smI[32 * RG];

    const int t = threadIdx.x;
    const int w = t >> 6, lane = t & 63;
    const int q = lane >> 4, m16 = lane & 15;
    const int d0 = blockIdx.x * 32;
    const int r0 = blockIdx.y * RG;
    const bool isLast = (blockIdx.y == gridDim.y - 1);
    const int colb = w * 32;
    const int cb16 = colb >> 4;                 // base coltile index
    const int fo = m16 * 32 + q * 8;            // lane offset within a 512-short fragment
    const bool gat = t < 32 * NCH;
    const int grow = t / NCH, gcc = t % NCH;
    const int mb  = grow * (RG + 1);
    const int mbI = grow * RG;

    // ---- meta preload (this group's bins only) ----
    for (int i = t; i < 32 * (RG + 1); i += 256) {
        int row = i / (RG + 1), rr = i % (RG + 1);
        smO[i] = binoff[(d0 + row) * N_REL + r0 + rr];
    }
    for (int i = t; i < 32 * RG; i += 256) {
        int row = i / RG, rr = i % RG;
        smI[i] = inv[(d0 + row) * N_REL + r0 + rr];
    }
    lds_barrier();

    f4v acc[2][2];
#pragma unroll
    for (int rt = 0; rt < 2; ++rt)
#pragma unroll
        for (int ct = 0; ct < 2; ++ct) acc[rt][ct] = f4v{0.f, 0.f, 0.f, 0.f};

    // ---- staged-edge pipeline state ----
    us8v gE[4][CP8];
#pragma unroll
    for (int e = 0; e < 4; ++e)
#pragma unroll
        for (int j = 0; j < CP8; ++j) gE[e][j] = us8v{};
    int sx[4] = {0, 0, 0, 0};

    if (gat) {
        const int so = smO[mb], cnt = smO[mb + 1] - so;
        int s0 = ssrc[so], s1 = ssrc[so + 1], s2 = ssrc[so + 2], s3 = ssrc[so + 3]; // pad-safe
        if (cnt >= 1) {
            const unsigned short* gp = G + (size_t)s0 * ROW + gcc * CW;
#pragma unroll
            for (int j = 0; j < CP8; ++j) gE[0][j] = *(const us8v*)(gp + j * 8);
        }
        if (cnt >= 2) {
            const unsigned short* gp = G + (size_t)s1 * ROW + gcc * CW;
#pragma unroll
            for (int j = 0; j < CP8; ++j) gE[1][j] = *(const us8v*)(gp + j * 8);
        }
        if (cnt >= 3) {
            const unsigned short* gp = G + (size_t)s2 * ROW + gcc * CW;
#pragma unroll
            for (int j = 0; j < CP8; ++j) gE[2][j] = *(const us8v*)(gp + j * 8);
        }
        if (cnt >= 4) {
            const unsigned short* gp = G + (size_t)s3 * ROW + gcc * CW;
#pragma unroll
            for (int j = 0; j < CP8; ++j) gE[3][j] = *(const us8v*)(gp + j * 8);
        }
        if (RG > 1) {
            const int so1 = smO[mb + 1];
            sx[0] = ssrc[so1]; sx[1] = ssrc[so1 + 1];
            sx[2] = ssrc[so1 + 2]; sx[3] = ssrc[so1 + 3];
        }
    }

    // B fragments for it=0 (fragment-major: contiguous 1 KB per load)
    bf8v bfr[2][KT];
#pragma unroll
    for (int ct = 0; ct < 2; ++ct) {
#pragma unroll
        for (int ks = 0; ks < KT; ++ks)
            bfr[ct][ks] = *(const bf8v*)(Bw + (size_t)r0 * (HID * ROW)
                              + ((cb16 + ct) * KT + ks) * 512 + fo);
    }

    for (int it = 0; it < RG; ++it) {
        unsigned short* Ab = As[it & 1];
        // ---- gather (consumes staged edges) + pre-barrier prefetch issue ----
        if (gat) {
            const int so = smO[mb + it], eo = smO[mb + it + 1];
            const int cnt = eo - so;
            const float m2 = cnt >= 2 ? 1.f : 0.f;
            const float m3 = cnt >= 3 ? 1.f : 0.f;
            const float m4 = cnt >= 4 ? 1.f : 0.f;
            float a[CW];
#pragma unroll
            for (int j = 0; j < CP8; ++j)
#pragma unroll
                for (int k = 0; k < 8; ++k)
                    a[j * 8 + k] = b2f(gE[0][j][k]) + m2 * b2f(gE[1][j][k])
                                 + m3 * b2f(gE[2][j][k]) + m4 * b2f(gE[3][j][k]);
            for (int p = so + 4; p < eo; ++p) {     // rare tail (P ~2e-3)
                const unsigned short* gp = G + (size_t)ssrc[p] * ROW + gcc * CW;
#pragma unroll
                for (int j = 0; j < CP8; ++j) {
                    us8v g = *(const us8v*)(gp + j * 8);
#pragma unroll
                    for (int k = 0; k < 8; ++k) a[j * 8 + k] += b2f(g[k]);
                }
            }
            const float iv = smI[mbI + it];
            unsigned short* wp = &Ab[grow * LSS + gcc * CW];
#pragma unroll
            for (int j = 0; j < CP8; ++j) {
                us8v sv;
#pragma unroll
                for (int k = 0; k < 8; ++k) sv[k] = f2b(a[j * 8 + k] * iv);
                *(us8v*)(wp + j * 8) = sv;
            }

            // pre-barrier: issue it+1's staged edges + srcs for it+2
            if (it + 1 < RG) {
                const int c1 = smO[mb + it + 2] - smO[mb + it + 1];
                if (c1 >= 1) {
                    const unsigned short* gp = G + (size_t)sx[0] * ROW + gcc * CW;
#pragma unroll
                    for (int j = 0; j < CP8; ++j) gE[0][j] = *(const us8v*)(gp + j * 8);
                }
                if (c1 >= 2) {
                    const unsigned short* gp = G + (size_t)sx[1] * ROW + gcc * CW;
#pragma unroll
                    for (int j = 0; j < CP8; ++j) gE[1][j] = *(const us8v*)(gp + j * 8);
                }
                if (c1 >= 3) {
                    const unsigned short* gp = G + (size_t)sx[2] * ROW + gcc * CW;
#pragma unroll
                    for (int j = 0; j < CP8; ++j) gE[2][j] = *(const us8v*)(gp + j * 8);
                }
                if (c1 >= 4) {
                    const unsigned short* gp = G + (size_t)sx[3] * ROW + gcc * CW;
#pragma unroll
                    for (int j = 0; j < CP8; ++j) gE[3][j] = *(const us8v*)(gp + j * 8);
                }
                if (it + 2 < RG) {
                    const int so2 = smO[mb + it + 2];
                    sx[0] = ssrc[so2]; sx[1] = ssrc[so2 + 1];
                    sx[2] = ssrc[so2 + 2]; sx[3] = ssrc[so2 + 3];
                }
            }
        }
        lds_barrier();   // LDS-only drain: global prefetches stay in flight

        // ---- A fragments + MFMA ----
#pragma unroll
        for (int rt = 0; rt < 2; ++rt) {
            const unsigned short* ar = &Ab[(m16 + 16 * rt) * LSS];
#pragma unroll
            for (int ks = 0; ks < KT; ++ks) {
                bf8v af = *(const bf8v*)(ar + ks * 32 + q * 8);
                acc[rt][0] = __builtin_amdgcn_mfma_f32_16x16x32_bf16(af, bfr[0][ks], acc[rt][0], 0, 0, 0);
                acc[rt][1] = __builtin_amdgcn_mfma_f32_16x16x32_bf16(af, bfr[1][ks], acc[rt][1], 0, 0, 0);
            }
        }

        // ---- B fragments for it+1 (root weights after last relation of last group) ----
        const unsigned short* Bp = (it + 1 < RG) ? (Bw + (size_t)(r0 + it + 1) * (HID * ROW))
                                                 : (isLast ? Br : nullptr);
        if (Bp) {
#pragma unroll
            for (int ct = 0; ct < 2; ++ct) {
#pragma unroll
                for (int ks = 0; ks < KT; ++ks)
                    bfr[ct][ks] = *(const bf8v*)(Bp + ((cb16 + ct) * KT + ks) * 512 + fo);
            }
        }
    }

    // ---- root transform (last group only): A straight from global ----
    if (isLast) {
#pragma unroll
        for (int rt = 0; rt < 2; ++rt) {
#pragma unroll
            for (int ks = 0; ks < KT; ++ks) {
                bf8v af = *(const bf8v*)(G + (size_t)(d0 + m16 + 16 * rt) * ROW + ks * 32 + q * 8);
                acc[rt][0] = __builtin_amdgcn_mfma_f32_16x16x32_bf16(af, bfr[0][ks], acc[rt][0], 0, 0, 0);
                acc[rt][1] = __builtin_amdgcn_mfma_f32_16x16x32_bf16(af, bfr[1][ks], acc[rt][1], 0, 0, 0);
            }
        }
    }

    // ---- epilogue: NONTEMPORAL fp32 partial stores (keep L2 for G/B) ----
    float* pb = part + (size_t)blockIdx.y * N_NODES * HID;
#pragma unroll
    for (int ct = 0; ct < 2; ++ct) {
        const int col = colb + 16 * ct + m16;
#pragma unroll
        for (int rt = 0; rt < 2; ++rt) {
#pragma unroll
            for (int g = 0; g < 4; ++g) {
                const int rr = 16 * rt + q * 4 + g;
                __builtin_nontemporal_store(acc[rt][ct][g],
                    &pb[(size_t)(d0 + rr) * HID + col]);
            }
        }
    }
}

// ======== reduces (nontemporal partial loads) ========
__global__ __launch_bounds__(256) void reduce1_k(
    const float* __restrict__ part, const float* __restrict__ b1,
    unsigned short* __restrict__ h1b) {
    int i = blockIdx.x * 256 + threadIdx.x;   // float4 index
    if (i >= N_NODES * HID / 4) return;
    const size_t S = (size_t)N_NODES * HID;
    float4 bb = *(const float4*)(b1 + ((i * 4) & 127));
    float r0 = bb.x, r1 = bb.y, r2 = bb.z, r3 = bb.w;
#pragma unroll
    for (int p = 0; p < 2; ++p) {
        const float* pp = part + p * S + (size_t)i * 4;
        r0 += __builtin_nontemporal_load(pp + 0);
        r1 += __builtin_nontemporal_load(pp + 1);
        r2 += __builtin_nontemporal_load(pp + 2);
        r3 += __builtin_nontemporal_load(pp + 3);
    }
    us4v v;
    v[0] = f2b(fmaxf(r0, 0.0f));
    v[1] = f2b(fmaxf(r1, 0.0f));
    v[2] = f2b(fmaxf(r2, 0.0f));
    v[3] = f2b(fmaxf(r3, 0.0f));
    *(us4v*)(h1b + (size_t)i * 4) = v;
}

__global__ __launch_bounds__(256) void reduce2_k(
    const float* __restrict__ part, const float* __restrict__ b2,
    float* __restrict__ out) {
    int i = blockIdx.x * 256 + threadIdx.x;   // float4 index
    if (i >= N_NODES * HID / 4) return;
    const size_t S = (size_t)N_NODES * HID;
    float4 bb = *(const float4*)(b2 + ((i * 4) & 127));
    float r0 = bb.x, r1 = bb.y, r2 = bb.z, r3 = bb.w;
#pragma unroll
    for (int p = 0; p < 4; ++p) {
        const float* pp = part + p * S + (size_t)i * 4;
        r0 += __builtin_nontemporal_load(pp + 0);
        r1 += __builtin_nontemporal_load(pp + 1);
        r2 += __builtin_nontemporal_load(pp + 2);
        r3 += __builtin_nontemporal_load(pp + 3);
    }
    float4 r; r.x = r0; r.y = r1; r.z = r2; r.w = r3;
    ((float4*)out)[i] = r;
}

extern "C" void kernel_launch(void* const* d_in, const int* in_sizes, int n_in,
                              void* d_out, int out_size, void* d_ws, size_t ws_size,
                              hipStream_t stream) {
    const int*   ei    = (const int*)d_in[0];   // [2, E]
    const int*   et    = (const int*)d_in[1];   // [E]
    const float* x     = (const float*)d_in[2]; // [N, 16]
    const float* W1    = (const float*)d_in[3]; // [32, 16, 128]
    const float* root1 = (const float*)d_in[4]; // [16, 128]
    const float* b1    = (const float*)d_in[5]; // [128]
    const float* W2    = (const float*)d_in[6]; // [32, 128, 128]
    const float* root2 = (const float*)d_in[7]; // [128, 128]
    const float* b2    = (const float*)d_in[8]; // [128]
    float* out = (float*)d_out;

    // ---- workspace layout (~60 MB) ----
    char* ws = (char*)d_ws;
    size_t off = 0;
    auto alloc = [&](size_t bytes) { void* p = ws + off; off = (off + bytes + 63) & ~(size_t)63; return p; };
    int*   hist    = (int*)  alloc((size_t)NB * 4);
    int*   binoff  = (int*)  alloc((size_t)(NB + 1) * 4);
    int*   cursors = (int*)  alloc((size_t)NB * 4);
    float* inv     = (float*)alloc((size_t)NB * 4);
    int*   bsum    = (int*)  alloc(625 * 4);
    int*   bbase   = (int*)  alloc(625 * 4);
    int*   ssrc    = (int*)  alloc((size_t)(N_EDGES + 4) * 4);
    unsigned short* xb  = (unsigned short*)alloc((size_t)N_NODES * 32 * 2);
    unsigned short* h1b = (unsigned short*)alloc((size_t)N_NODES * HID * 2);
    unsigned short* w1t = (unsigned short*)alloc((size_t)N_REL * HID * 32 * 2);
    unsigned short* r1t = (unsigned short*)alloc((size_t)HID * 32 * 2);
    unsigned short* w2t = (unsigned short*)alloc((size_t)N_REL * HID * HID * 2);
    unsigned short* r2t = (unsigned short*)alloc((size_t)HID * HID * 2);
    float* part = (float*)alloc((size_t)4 * N_NODES * HID * 4);   // 4 partials, reused both layers

    const int* src = ei;
    const int* dst = ei + N_EDGES;

    hipMemsetAsync(hist, 0, (size_t)NB * 4, stream);
    pre1_k<<<(PRE_TOT + 255) / 256, 256, 0, stream>>>(
        dst, et, x, W1, root1, W2, root2, hist, xb, w1t, r1t, w2t, r2t);
    scan1_k<<<NB / 1024, 256, 0, stream>>>(hist, binoff, bsum, inv);
    scan2_k<<<1, 1024, 0, stream>>>(bsum, bbase);
    scan3_k<<<(NB + 255) / 256, 256, 0, stream>>>(binoff, bbase, cursors);
    scatter_k<<<(N_EDGES + 255) / 256, 256, 0, stream>>>(src, dst, et, cursors, ssrc);

    // ---- layer 1: 2 relation groups (16 rels each; last adds root) ----
    gemm_f<1, 40, 8, 16><<<dim3(625, 2), 256, 0, stream>>>(
        binoff, inv, ssrc, xb, w1t, r1t, part);
    reduce1_k<<<(N_NODES * HID / 4 + 255) / 256, 256, 0, stream>>>(part, b1, h1b);

    // ---- layer 2: 4 relation groups (8 rels each; last adds root) ----
    gemm_f<4, 136, 16, 8><<<dim3(625, 4), 256, 0, stream>>>(
        binoff, inv, ssrc, h1b, w2t, r2t, part);
    reduce2_k<<<(N_NODES * HID / 4 + 255) / 256, 256, 0, stream>>>(part, b2, out);
}